// Round 3
// baseline (747.309 us; speedup 1.0000x reference)
//
#include <hip/hip_runtime.h>
#include <hip/hip_bf16.h>
#include <hip/hip_cooperative_groups.h>

namespace cg = cooperative_groups;

typedef unsigned short u16;
typedef unsigned int u32;
typedef short short8v __attribute__((ext_vector_type(8)));
typedef float f32x4 __attribute__((ext_vector_type(4)));

#define NN 50000
#define EE 800000
#define PP 65536
#define NBKT 196      // node buckets of 256: ceil(NN/256)
#define NHB 256       // histogram blocks (edge chunks of 3125)
#define ECH 3125      // edges per histogram block: 256*3125 = EE exactly

// ---- static device workspace. RULE (r3): device-global addresses never cross
// the host/device boundary — kernels resolve them via compile-time IDs.
__device__ __align__(256) float g_deg_norm[NN];
__device__ __align__(256) int   g_row_ptr[NN + 1];
__device__ __align__(256) int   g_rank[EE];          // intra-node rank
__device__ __align__(256) int   g_bh[NBKT * NHB];    // [bucket][block] counts
__device__ __align__(256) int   g_bbase[NBKT * NHB]; // exclusive scan over blocks
__device__ __align__(256) int   g_btot[NBKT];
__device__ __align__(256) u32   g_ebkt[EE];          // bucket-grouped: src | dlow<<16
__device__ __align__(256) float g_wtmp[EE];          // raw w (f32), bucket-grouped
__device__ __align__(256) float g_w2[EE];            // raw w, CSR order
__device__ __align__(256) u32   g_ecwp[EE];          // final: src(16b) | w_bf16(16b)
__device__ __align__(256) u16   g_X16[NN * 128];     // x bf16, row-major
__device__ __align__(256) u16   g_H1[NN * 128];      // hop outs / 2x Z (layer-3 Horner)
__device__ __align__(256) u16   g_H2[NN * 128];
__device__ __align__(256) u16   g_H3[NN * 128];
__device__ __align__(256) u16   g_Hn0[NN * 128];
__device__ __align__(256) u16   g_Hn1[NN * 128];
__device__ __align__(256) u16   g_Hf16[NN * 64];     // final h (bf16), row-major
__device__ __align__(256) u16   g_Bf1[512 * 128];    // W in MFMA B-fragment order
__device__ __align__(256) u16   g_Bf2[512 * 128];
__device__ __align__(256) u16   g_Bf3[512 * 64];
__device__ __align__(256) u16   g_Pf1[4 * 64 * 8];   // P1 in B-frag order
__device__ int g_f32mode;  // 1 if harness float tensors are float32, 0 if bf16

__device__ __forceinline__ float bf2f(u16 u) {
  union { u32 i; float f; } v;
  v.i = ((u32)u) << 16;
  return v.f;
}
__device__ __forceinline__ u16 f2bf(float f) {
  u32 x = __float_as_uint(f);
  u32 r = (x + 0x7fffu + ((x >> 16) & 1u)) >> 16;  // RNE
  return (u16)r;
}
__device__ __forceinline__ float ldf(const void* p, int i, int m) {
  return m ? ((const float*)p)[i] : bf2f(((const u16*)p)[i]);
}

// buffer IDs: 0 = X16, 3 = Hn0, 4 = Hn1, 5 = H1, 6 = H2, 7 = H3 (stride 128)
template <int ID>
__device__ __forceinline__ u16* sel_buf() {
  if (ID == 0) return g_X16;
  if (ID == 3) return g_Hn0;
  if (ID == 4) return g_Hn1;
  if (ID == 5) return g_H1;
  if (ID == 6) return g_H2;
  return g_H3;
}
template <int ID>
__device__ __forceinline__ u16* sel_bf() {
  if (ID == 1) return g_Bf1;
  if (ID == 2) return g_Bf2;
  return g_Bf3;
}
// width-64 Z/T buffers for layer-3 Horner (carved from H1/H2/H3)
template <int ID>
__device__ __forceinline__ u16* zb() {
  if (ID == 8) return g_H1;                 // Z3
  if (ID == 9) return g_H1 + NN * 64;       // Z2
  if (ID == 10) return g_H2;                // Z1
  if (ID == 11) return g_H2 + NN * 64;      // Z0 (+bias)
  if (ID == 12) return g_H3;                // T ping
  return g_H3 + NN * 64;                    // 13: T pong
}

// ---------------- fused W/P conversion body (unchanged layout math)
template <int FOUT>
__device__ __forceinline__ void conv_w_body(const void* W, u16* dstbuf, int t, int m) {
  constexpr int NT = FOUT / 16;
  if (t >= 1024 * NT) return;
  int lane = t & 63;
  int rest = t >> 6;
  int nt = rest % NT;
  int s = (rest / NT) % 4;
  int kc = rest / (NT * 4);
  int kbase = kc * 128 + s * 32 + ((lane >> 4) << 3);
  int n = nt * 16 + (lane & 15);
  u16* dst = dstbuf + (size_t)t * 8;
#pragma unroll
  for (int j = 0; j < 8; ++j) dst[j] = f2bf(ldf(W, (kbase + j) * FOUT + n, m));
}

// ============================ cooperative prep (r15) ==========================
// One kernel, 4 grid syncs, replaces: probe, prep1, bucket_scan, bstart_scan,
// scatter_bucket, csr_finalize (6 launches + 5 inter-launch drains).
// Output: g_row_ptr, g_deg_norm, g_ecwp (src | dlow — w patched by hop1),
// g_w2 (raw f32 w in CSR order), g_X16, g_Bf*, g_Pf1, g_f32mode.
__global__ __launch_bounds__(256, 2) void coop_prep_kernel(
    const u16* __restrict__ x, const int* __restrict__ dst, const int* __restrict__ src,
    const void* __restrict__ w_edge, const void* __restrict__ W1, const void* __restrict__ W2,
    const void* __restrict__ W3, const void* __restrict__ P1) {
  cg::grid_group grid = cg::this_grid();
  __shared__ int lhist[256];
  __shared__ int lbase[256];
  __shared__ int sbstart[NBKT + 1];
  __shared__ int ws[4];
  __shared__ int scnt;
  int tid = threadIdx.x;

  // ---- P-1: dtype probe (block 0 only) ----
  if (blockIdx.x == 0) {
    if (tid == 0) scnt = 0;
    __syncthreads();
    int c = 0;
    for (int i = tid; i < 2048; i += 256) {
      u16 u = x[2 * i];
      int e = (u >> 7) & 0xFF;
      if (e >= 0x8F) c++;
    }
    atomicAdd(&scnt, c);
    __syncthreads();
    if (tid == 0) g_f32mode = (scnt > 64) ? 1 : 0;
  }
  grid.sync();
  int m = g_f32mode;

  // ---- P0: convert x | bucket histogram | W/P conversion ----
  for (int vb = blockIdx.x; vb < 12500 + NHB + 81; vb += gridDim.x) {
    if (vb < 12500) {
      int i = vb * 256 + tid;  // u32-pair index, exact: 12500*256 = NN*64
      u32 lo = f2bf(ldf(x, 2 * i, m));
      u32 hi = f2bf(ldf(x, 2 * i + 1, m));
      ((u32*)g_X16)[i] = lo | (hi << 16);
    } else if (vb < 12500 + NHB) {
      int hb = vb - 12500;
      for (int i = tid; i < NBKT; i += 256) lhist[i] = 0;
      __syncthreads();
      int base = hb * ECH;
      for (int i = tid; i < ECH; i += 256) atomicAdd(&lhist[dst[base + i] >> 8], 1);
      __syncthreads();
      if (tid < NBKT) g_bh[tid * NHB + hb] = lhist[tid];
      __syncthreads();
    } else {
      int wb = vb - (12500 + NHB);
      if (wb < 32) {
        conv_w_body<128>(W1, g_Bf1, wb * 256 + tid, m);
      } else if (wb < 64) {
        conv_w_body<128>(W2, g_Bf2, (wb - 32) * 256 + tid, m);
      } else if (wb < 80) {
        conv_w_body<64>(W3, g_Bf3, (wb - 64) * 256 + tid, m);
      } else {
        int f = tid >> 6, lane = tid & 63;
        int ks = f >> 1, nt = f & 1;
        int quad = lane >> 4, arow = lane & 15;
#pragma unroll
        for (int j = 0; j < 8; ++j)
          g_Pf1[(size_t)tid * 8 + j] =
              f2bf(ldf(P1, (ks * 32 + quad * 8 + j) * 32 + nt * 16 + arow, m));
      }
    }
  }
  grid.sync();

  // ---- P1: per-bucket exclusive scan over blocks ----
  for (int vb = blockIdx.x; vb < NBKT; vb += gridDim.x) {
    int v = g_bh[vb * NHB + tid];
    int xx = v;
#pragma unroll
    for (int off = 1; off < 64; off <<= 1) {
      int y = __shfl_up(xx, off, 64);
      if ((tid & 63) >= off) xx += y;
    }
    if ((tid & 63) == 63) ws[tid >> 6] = xx;
    __syncthreads();
    int wp = 0;
    if (tid >= 64) wp += ws[0];
    if (tid >= 128) wp += ws[1];
    if (tid >= 192) wp += ws[2];
    g_bbase[vb * NHB + tid] = wp + xx - v;  // exclusive within bucket
    if (tid == 255) g_btot[vb] = wp + xx;
    __syncthreads();
  }
  grid.sync();

  // ---- local bucket-start scan (every block; replaces bstart_scan kernel) ----
  {
    int v = (tid < NBKT) ? g_btot[tid] : 0;
    int xx = v;
#pragma unroll
    for (int off = 1; off < 64; off <<= 1) {
      int y = __shfl_up(xx, off, 64);
      if ((tid & 63) >= off) xx += y;
    }
    if ((tid & 63) == 63) ws[tid >> 6] = xx;
    __syncthreads();
    int wp = 0;
    if (tid >= 64) wp += ws[0];
    if (tid >= 128) wp += ws[1];
    if (tid >= 192) wp += ws[2];
    if (tid < NBKT) sbstart[tid] = wp + xx - v;
    if (tid == 0) sbstart[NBKT] = EE;
    __syncthreads();
  }

  // ---- P2: scatter edges into bucket-grouped order (LDS-atomic local rank) ----
  for (int vb = blockIdx.x; vb < NHB; vb += gridDim.x) {
    for (int i = tid; i < NBKT; i += 256) {
      lhist[i] = 0;
      lbase[i] = sbstart[i] + g_bbase[i * NHB + vb];
    }
    __syncthreads();
    int base = vb * ECH;
    for (int i = tid; i < ECH; i += 256) {
      int e = base + i;
      int d = dst[e];
      int s = src[e];
      float w = ldf(w_edge, e, m);
      int bkt = d >> 8;
      int r = atomicAdd(&lhist[bkt], 1);
      int pos = lbase[bkt] + r;
      g_ebkt[pos] = (u32)s | ((u32)(d & 255) << 16);
      g_wtmp[pos] = w;
    }
    __syncthreads();
  }
  grid.sync();

  // ---- P3: per-bucket CSR finalize ----
  for (int vb = blockIdx.x; vb < NBKT; vb += gridDim.x) {
    int bs = sbstart[vb], be = sbstart[vb + 1];
    lhist[tid] = 0;
    __syncthreads();
    for (int i = bs + tid; i < be; i += 256) {
      int dlow = (g_ebkt[i] >> 16) & 0xFF;
      g_rank[i] = atomicAdd(&lhist[dlow], 1);
    }
    __syncthreads();
    int v = lhist[tid];
    int xx = v;
#pragma unroll
    for (int off = 1; off < 64; off <<= 1) {
      int y = __shfl_up(xx, off, 64);
      if ((tid & 63) >= off) xx += y;
    }
    if ((tid & 63) == 63) ws[tid >> 6] = xx;
    __syncthreads();
    int wp = 0;
    if (tid >= 64) wp += ws[0];
    if (tid >= 128) wp += ws[1];
    if (tid >= 192) wp += ws[2];
    int excl = wp + xx - v;
    lbase[tid] = excl;
    int node = vb * 256 + tid;
    if (node < NN) {
      g_row_ptr[node] = bs + excl;
      g_deg_norm[node] = rsqrtf((float)(v > 0 ? v : 1));
    }
    if (vb == NBKT - 1 && tid == 0) g_row_ptr[NN] = EE;
    __syncthreads();
    for (int i = bs + tid; i < be; i += 256) {
      u32 p = g_ebkt[i];
      int dlow = (p >> 16) & 0xFF;
      int pos = bs + lbase[dlow] + g_rank[i];
      g_ecwp[pos] = p;       // src in low 16; w field written by hop1 (FINW)
      g_w2[pos] = g_wtmp[i];
    }
    __syncthreads();
  }
}

// --------------------------------------------------------- width-128 hop (r15)
// out[n][f] = deg_norm[n] * sum_e w[e] * in[col[e]][f]
// One wave per node. Lane = (edge-group g=lane>>4, feature-block q=lane&15).
// FINW (layer-1 hop1 only): w comes from g_w2[e] * deg_norm[src] in f32, and
// the finalized bf16-packed edge is written back for the 8 later hops
// (replaces the standalone wfinal kernel; own-segment writes -> race-free).
template <int IN_ID, int OUT_ID, bool FINW>
__global__ __launch_bounds__(256) void hop_kernel() {
  int wv = __builtin_amdgcn_readfirstlane(threadIdx.x >> 6);  // wave-uniform -> SGPR
  int n = blockIdx.x * 4 + wv;
  if (n >= NN) return;
  int lane = threadIdx.x & 63;
  int g = lane >> 4;   // edge group 0..3
  int q = lane & 15;   // features q*8 .. q*8+7
  const u16* inf = sel_buf<IN_ID>() + q * 8;
  int beg = g_row_ptr[n], end = g_row_ptr[n + 1];
  float a0[8], a1[8];
#pragma unroll
  for (int j = 0; j < 8; ++j) { a0[j] = 0.f; a1[j] = 0.f; }
  int e = beg;
  for (; e + 16 <= end; e += 16) {
    u32 p0 = g_ecwp[e + g];
    u32 p1 = g_ecwp[e + 4 + g];
    u32 p2 = g_ecwp[e + 8 + g];
    u32 p3 = g_ecwp[e + 12 + g];
    float wA, wB, wC, wD;
    if (FINW) {
      float r0 = g_w2[e + g], r1 = g_w2[e + 4 + g], r2 = g_w2[e + 8 + g], r3 = g_w2[e + 12 + g];
      wA = r0 * g_deg_norm[p0 & 0xFFFFu];
      wB = r1 * g_deg_norm[p1 & 0xFFFFu];
      wC = r2 * g_deg_norm[p2 & 0xFFFFu];
      wD = r3 * g_deg_norm[p3 & 0xFFFFu];
    } else {
      wA = bf2f((u16)(p0 >> 16));
      wB = bf2f((u16)(p1 >> 16));
      wC = bf2f((u16)(p2 >> 16));
      wD = bf2f((u16)(p3 >> 16));
    }
    short8v u0 = *(const short8v*)(inf + (p0 & 0xFFFFu) * 128);
    short8v u1 = *(const short8v*)(inf + (p1 & 0xFFFFu) * 128);
    short8v u2 = *(const short8v*)(inf + (p2 & 0xFFFFu) * 128);
    short8v u3 = *(const short8v*)(inf + (p3 & 0xFFFFu) * 128);
#pragma unroll
    for (int j = 0; j < 8; ++j) {
      a0[j] += wA * bf2f((u16)u0[j]);
      a1[j] += wB * bf2f((u16)u1[j]);
      a0[j] += wC * bf2f((u16)u2[j]);
      a1[j] += wD * bf2f((u16)u3[j]);
    }
    if (FINW && q == 0) {
      g_ecwp[e + g]      = (p0 & 0xFFFFu) | ((u32)f2bf(wA) << 16);
      g_ecwp[e + 4 + g]  = (p1 & 0xFFFFu) | ((u32)f2bf(wB) << 16);
      g_ecwp[e + 8 + g]  = (p2 & 0xFFFFu) | ((u32)f2bf(wC) << 16);
      g_ecwp[e + 12 + g] = (p3 & 0xFFFFu) | ((u32)f2bf(wD) << 16);
    }
  }
  for (; e + 8 <= end; e += 8) {
    u32 p0 = g_ecwp[e + g];
    u32 p1 = g_ecwp[e + 4 + g];
    float wA, wB;
    if (FINW) {
      wA = g_w2[e + g] * g_deg_norm[p0 & 0xFFFFu];
      wB = g_w2[e + 4 + g] * g_deg_norm[p1 & 0xFFFFu];
    } else {
      wA = bf2f((u16)(p0 >> 16));
      wB = bf2f((u16)(p1 >> 16));
    }
    short8v u0 = *(const short8v*)(inf + (p0 & 0xFFFFu) * 128);
    short8v u1 = *(const short8v*)(inf + (p1 & 0xFFFFu) * 128);
#pragma unroll
    for (int j = 0; j < 8; ++j) {
      a0[j] += wA * bf2f((u16)u0[j]);
      a1[j] += wB * bf2f((u16)u1[j]);
    }
    if (FINW && q == 0) {
      g_ecwp[e + g]     = (p0 & 0xFFFFu) | ((u32)f2bf(wA) << 16);
      g_ecwp[e + 4 + g] = (p1 & 0xFFFFu) | ((u32)f2bf(wB) << 16);
    }
  }
  for (; e < end; e += 4) {  // masked tail, <=7 left -> <=2 iterations
    if (e + g < end) {
      u32 p = g_ecwp[e + g];
      float w;
      if (FINW) w = g_w2[e + g] * g_deg_norm[p & 0xFFFFu];
      else      w = bf2f((u16)(p >> 16));
      short8v u = *(const short8v*)(inf + (p & 0xFFFFu) * 128);
#pragma unroll
      for (int j = 0; j < 8; ++j) a0[j] += w * bf2f((u16)u[j]);
      if (FINW && q == 0) g_ecwp[e + g] = (p & 0xFFFFu) | ((u32)f2bf(w) << 16);
    }
  }
  float s[8];
#pragma unroll
  for (int j = 0; j < 8; ++j) {
    float v = a0[j] + a1[j];
    v += __shfl_xor(v, 16, 64);
    v += __shfl_xor(v, 32, 64);
    s[j] = v;  // every lane now has totals for features q*8+j
  }
  float dn = g_deg_norm[n];
  // group g writes the u32 covering features q*8+2g, q*8+2g+1 -> 256B coalesced
  u32 outv = (u32)f2bf(s[2 * g] * dn) | ((u32)f2bf(s[2 * g + 1] * dn) << 16);
  *(u32*)(sel_buf<OUT_ID>() + n * 128 + q * 8 + 2 * g) = outv;
}

// ------------------------------------------------- width-64 hop with addend
// T_out[n] = deg_norm[n] * (A T_in)[n] + Add[n]   (layer-3 Horner step)
template <int IN_ID, int ADD_ID, int OUT_ID, bool FINAL>
__global__ __launch_bounds__(256) void hop64_kernel(void* __restrict__ outp) {
  int wv = __builtin_amdgcn_readfirstlane(threadIdx.x >> 6);
  int n = blockIdx.x * 4 + wv;
  if (n >= NN) return;
  int lane = threadIdx.x & 63;
  int g = lane >> 3;  // edge group 0..7
  int q = lane & 7;   // features q*8 .. q*8+7
  const u16* inf = zb<IN_ID>() + 2 * q * 4;  // q*8
  int beg = g_row_ptr[n], end = g_row_ptr[n + 1];
  float a0[8], a1[8];
#pragma unroll
  for (int j = 0; j < 8; ++j) { a0[j] = 0.f; a1[j] = 0.f; }
  int e = beg;
  for (; e + 16 <= end; e += 16) {
    u32 p0 = g_ecwp[e + g];
    u32 p1 = g_ecwp[e + 8 + g];
    short8v u0 = *(const short8v*)(inf + (p0 & 0xFFFFu) * 64);
    short8v u1 = *(const short8v*)(inf + (p1 & 0xFFFFu) * 64);
    float w0 = bf2f((u16)(p0 >> 16));
    float w1 = bf2f((u16)(p1 >> 16));
#pragma unroll
    for (int j = 0; j < 8; ++j) {
      a0[j] += w0 * bf2f((u16)u0[j]);
      a1[j] += w1 * bf2f((u16)u1[j]);
    }
  }
  for (; e + 8 <= end; e += 8) {
    u32 p = g_ecwp[e + g];
    short8v u = *(const short8v*)(inf + (p & 0xFFFFu) * 64);
    float w = bf2f((u16)(p >> 16));
#pragma unroll
    for (int j = 0; j < 8; ++j) a0[j] += w * bf2f((u16)u[j]);
  }
  if (e < end) {  // masked tail, <=7 left, 8 groups -> one iteration
    if (e + g < end) {
      u32 p = g_ecwp[e + g];
      short8v u = *(const short8v*)(inf + (p & 0xFFFFu) * 64);
      float w = bf2f((u16)(p >> 16));
#pragma unroll
      for (int j = 0; j < 8; ++j) a0[j] += w * bf2f((u16)u[j]);
    }
  }
  float s[8];
#pragma unroll
  for (int j = 0; j < 8; ++j) {
    float v = a0[j] + a1[j];
    v += __shfl_xor(v, 8, 64);
    v += __shfl_xor(v, 16, 64);
    v += __shfl_xor(v, 32, 64);
    s[j] = v;
  }
  float dn = g_deg_norm[n];
  if (g < 4) {  // groups 0..3 write the 128-B output row
    int ci = n * 64 + q * 8 + 2 * g;
    u32 ad = *(const u32*)(zb<ADD_ID>() + ci);
    float r0 = s[2 * g] * dn + bf2f((u16)ad);
    float r1 = s[2 * g + 1] * dn + bf2f((u16)(ad >> 16));
    if (!FINAL) {
      *(u32*)(zb<OUT_ID>() + ci) = (u32)f2bf(r0) | ((u32)f2bf(r1) << 16);
    } else {
      *(u32*)(g_Hf16 + ci) = (u32)f2bf(r0) | ((u32)f2bf(r1) << 16);
      if (g_f32mode) {
        ((float*)outp)[2 * PP + ci] = r0;
        ((float*)outp)[2 * PP + ci + 1] = r1;
      } else {
        ((u32*)((u16*)outp + 2 * PP))[ci >> 1] = (u32)f2bf(r0) | ((u32)f2bf(r1) << 16);
      }
    }
  }
}

// -------------------------------------------------- MFMA GEMM (FOUT=128, r12)
// C(M x 128) = [f0 | H1 | H2 | H3] (Mx512, row-major) @ B + bias, ReLU.
template <int A0_ID, int C_ID, int BF_ID>
__global__ __launch_bounds__(256) void gemm_kernel(const void* __restrict__ bias) {
  constexpr int NT = 8;
  const u16* Bf = sel_bf<BF_ID>();
  int tid = threadIdx.x;
  int lane = tid & 63, wv = tid >> 6;
  int quad = lane >> 4, arow = lane & 15;
  int mbase = blockIdx.x * 64 + wv * 16;
  if (mbase >= NN) return;  // no barriers -> safe (NN % 16 == 0)
  int row0 = mbase + arow;

  f32x4 acc[NT];
#pragma unroll
  for (int nt = 0; nt < NT; ++nt) acc[nt] = (f32x4){0.f, 0.f, 0.f, 0.f};

#pragma unroll
  for (int kc = 0; kc < 4; ++kc) {
    const u16* base = (kc == 0) ? sel_buf<A0_ID>() : (kc == 1) ? g_H1 : (kc == 2) ? g_H2 : g_H3;
#pragma unroll
    for (int s = 0; s < 4; ++s) {
      int ko = s * 32 + quad * 8;
      short8v av = *(const short8v*)(base + row0 * 128 + ko);
      const u16* bp = Bf + (size_t)(((kc * 4 + s) * NT) * 64 + lane) * 8;
#pragma unroll
      for (int nt = 0; nt < NT; ++nt) {
        short8v b = *(const short8v*)(bp + nt * 64 * 8);
        acc[nt] = __builtin_amdgcn_mfma_f32_16x16x32_bf16(av, b, acc[nt], 0, 0, 0);
      }
    }
  }

  int m = g_f32mode;
  float bn[NT];
#pragma unroll
  for (int nt = 0; nt < NT; ++nt) bn[nt] = ldf(bias, nt * 16 + arow, m);
#pragma unroll
  for (int i = 0; i < 4; ++i) {
    int row = mbase + quad * 4 + i;  // C/D: col=lane&15, row=quad*4+reg
#pragma unroll
    for (int nt = 0; nt < NT; ++nt) {
      float v = acc[nt][i] + bn[nt];
      v = v > 0.f ? v : 0.f;  // ReLU (layers 1,2 only)
      sel_buf<C_ID>()[row * 128 + nt * 16 + arow] = f2bf(v);
    }
  }
}

// --------------------- fused small GEMM: Z_k = Hn1 @ W3[kc] for kc=0..3 (r13)
__global__ __launch_bounds__(256) void gemm64_all_kernel(const void* __restrict__ bias) {
  int tid = threadIdx.x;
  int lane = tid & 63, wv = tid >> 6;
  int quad = lane >> 4, arow = lane & 15;
  int mbase = blockIdx.x * 64 + wv * 16;
  if (mbase >= NN) return;
  int row0 = mbase + arow;

  f32x4 acc[4][4];  // [kc][nt]
#pragma unroll
  for (int kc = 0; kc < 4; ++kc)
#pragma unroll
    for (int nt = 0; nt < 4; ++nt) acc[kc][nt] = (f32x4){0.f, 0.f, 0.f, 0.f};

#pragma unroll
  for (int s = 0; s < 4; ++s) {
    int ko = s * 32 + quad * 8;
    short8v av = *(const short8v*)(g_Hn1 + row0 * 128 + ko);
#pragma unroll
    for (int kc = 0; kc < 4; ++kc) {
      const u16* bp = g_Bf3 + (size_t)(((kc * 4 + s) * 4) * 64 + lane) * 8;
#pragma unroll
      for (int nt = 0; nt < 4; ++nt) {
        short8v b = *(const short8v*)(bp + nt * 64 * 8);
        acc[kc][nt] = __builtin_amdgcn_mfma_f32_16x16x32_bf16(av, b, acc[kc][nt], 0, 0, 0);
      }
    }
  }

  int m = g_f32mode;
  float bn[4];
#pragma unroll
  for (int nt = 0; nt < 4; ++nt) bn[nt] = ldf(bias, nt * 16 + arow, m);
#pragma unroll
  for (int kc = 0; kc < 4; ++kc) {
    u16* Z = (kc == 0) ? zb<11>() : (kc == 1) ? zb<10>() : (kc == 2) ? zb<9>() : zb<8>();
#pragma unroll
    for (int i = 0; i < 4; ++i) {
      int row = mbase + quad * 4 + i;
#pragma unroll
      for (int nt = 0; nt < 4; ++nt) {
        float v = acc[kc][nt][i] + (kc == 0 ? bn[nt] : 0.f);
        Z[row * 64 + nt * 16 + arow] = f2bf(v);
      }
    }
  }
}

// ------------------------------------------------------------------ predictor
__global__ __launch_bounds__(256) void predictor_kernel(
    const int* __restrict__ pos_src, const int* __restrict__ pos_dst,
    const int* __restrict__ neg_src, const int* __restrict__ neg_dst,
    const void* __restrict__ pb1, const void* __restrict__ P2,
    const void* __restrict__ pb2, const void* __restrict__ P3, const void* __restrict__ pb3,
    void* __restrict__ out) {
  __shared__ float sP2[32 * 16];
  __shared__ float sb1[32], sb2[16], sP3[16];
  __shared__ float sb3;
  __shared__ float zt[4][16][33];
  int m = g_f32mode;
  int tid = threadIdx.x;
  for (int i = tid; i < 512; i += 256) sP2[i] = ldf(P2, i, m);
  if (tid < 32) sb1[tid] = ldf(pb1, tid, m);
  if (tid < 16) sb2[tid] = ldf(pb2, tid, m);
  if (tid < 16) sP3[tid] = ldf(P3, tid, m);
  if (tid == 0) sb3 = ldf(pb3, 0, m);
  __syncthreads();

  int wv = tid >> 6, lane = tid & 63;
  int quad = lane >> 4, arow = lane & 15;
  int base = (blockIdx.x * 4 + wv) * 16;
  int idx = base + arow;
  int s, d;
  if (idx < PP) { s = pos_src[idx]; d = pos_dst[idx]; }  // PP%16==0 -> wave-uniform
  else          { s = neg_src[idx - PP]; d = neg_dst[idx - PP]; }

  const u16* hs = g_Hf16 + s * 64 + quad * 8;
  const u16* hd = g_Hf16 + d * 64 + quad * 8;
  short8v zf[2];
#pragma unroll
  for (int ks = 0; ks < 2; ++ks) {
    short8v a = *(const short8v*)(hs + ks * 32);
    short8v b = *(const short8v*)(hd + ks * 32);
#pragma unroll
    for (int j = 0; j < 8; ++j)
      ((u16*)&zf[ks])[j] = f2bf(bf2f((u16)a[j]) * bf2f((u16)b[j]));
  }
  f32x4 acc[2];
  acc[0] = (f32x4){0.f, 0.f, 0.f, 0.f};
  acc[1] = (f32x4){0.f, 0.f, 0.f, 0.f};
#pragma unroll
  for (int ks = 0; ks < 2; ++ks) {
#pragma unroll
    for (int nt = 0; nt < 2; ++nt) {
      short8v bfr = *(const short8v*)(g_Pf1 + (size_t)((ks * 2 + nt) * 64 + lane) * 8);
      acc[nt] = __builtin_amdgcn_mfma_f32_16x16x32_bf16(zf[ks], bfr, acc[nt], 0, 0, 0);
    }
  }
#pragma unroll
  for (int nt = 0; nt < 2; ++nt) {
    float bn = sb1[nt * 16 + arow];
#pragma unroll
    for (int i = 0; i < 4; ++i) {
      float v = acc[nt][i] + bn;
      zt[wv][quad * 4 + i][nt * 16 + arow] = v > 0.f ? v : 0.2f * v;
    }
  }
  __syncthreads();
  float z2[4];
#pragma unroll
  for (int jj = 0; jj < 4; ++jj) z2[jj] = sb2[quad * 4 + jj];
  const float* zrow = &zt[wv][arow][0];
#pragma unroll
  for (int c = 0; c < 32; ++c) {
    float zc = zrow[c];
#pragma unroll
    for (int jj = 0; jj < 4; ++jj) z2[jj] += zc * sP2[c * 16 + quad * 4 + jj];
  }
  float o = 0.f;
#pragma unroll
  for (int jj = 0; jj < 4; ++jj) {
    float v = z2[jj] > 0.f ? z2[jj] : 0.2f * z2[jj];
    o += v * sP3[quad * 4 + jj];
  }
  o += __shfl_xor(o, 16, 64);
  o += __shfl_xor(o, 32, 64);
  o += sb3;
  if (quad == 0) {
    if (m) ((float*)out)[idx] = o;
    else   ((u16*)out)[idx] = f2bf(o);
  }
}

// ------------------------------------------------------------------- launch
extern "C" void kernel_launch(void* const* d_in, const int* in_sizes, int n_in,
                              void* d_out, int out_size, void* d_ws, size_t ws_size,
                              hipStream_t stream) {
  const u16* x       = (const u16*)d_in[0];
  const int* src     = (const int*)d_in[1];
  const int* dst     = (const int*)d_in[2];
  const void* w_edge = d_in[3];
  const int* pos_src = (const int*)d_in[4];
  const int* pos_dst = (const int*)d_in[5];
  const int* neg_src = (const int*)d_in[6];
  const int* neg_dst = (const int*)d_in[7];
  const void* W1 = d_in[8];
  const void* b1 = d_in[9];
  const void* W2 = d_in[10];
  const void* b2 = d_in[11];
  const void* W3 = d_in[12];
  const void* b3 = d_in[13];
  const void* P1  = d_in[14];
  const void* pb1 = d_in[15];
  const void* P2  = d_in[16];
  const void* pb2 = d_in[17];
  const void* P3  = d_in[18];
  const void* pb3 = d_in[19];
  (void)d_ws; (void)ws_size; (void)in_sizes; (void)n_in; (void)out_size;

  // --- cooperative prep: probe + convert + histogram + scans + CSR (1 launch) ---
  void* cargs[] = {(void*)&x, (void*)&dst, (void*)&src, (void*)&w_edge,
                   (void*)&W1, (void*)&W2, (void*)&W3, (void*)&P1};
  hipLaunchCooperativeKernel(coop_prep_kernel, dim3(512), dim3(256), cargs, 0, stream);

  int gHop = (NN + 3) / 4;
  int gGemm = (NN + 63) / 64;

  // --- Layer 1: f0 = x(bf16); hop1 finalizes edge weights (FINW) ---
  hop_kernel<0, 5, true><<<gHop, 256, 0, stream>>>();
  hop_kernel<5, 6, false><<<gHop, 256, 0, stream>>>();
  hop_kernel<6, 7, false><<<gHop, 256, 0, stream>>>();
  gemm_kernel<0, 3, 1><<<gGemm, 256, 0, stream>>>(b1);

  // --- Layer 2: f0 = Hn0 ---
  hop_kernel<3, 5, false><<<gHop, 256, 0, stream>>>();
  hop_kernel<5, 6, false><<<gHop, 256, 0, stream>>>();
  hop_kernel<6, 7, false><<<gHop, 256, 0, stream>>>();
  gemm_kernel<3, 4, 2><<<gGemm, 256, 0, stream>>>(b2);

  // --- Layer 3 (Horner): out = Z0+b3 + A(Z1 + A(Z2 + A Z3)), Z_k = Hn1@W3_k ---
  gemm64_all_kernel<<<gGemm, 256, 0, stream>>>(b3);  // Z3,Z2,Z1,Z0+b3 fused
  hop64_kernel<8, 9, 12, false><<<gHop, 256, 0, stream>>>(nullptr);   // T1 = A Z3 + Z2
  hop64_kernel<12, 10, 13, false><<<gHop, 256, 0, stream>>>(nullptr); // T2 = A T1 + Z1
  hop64_kernel<13, 11, 12, true><<<gHop, 256, 0, stream>>>(d_out);    // h = A T2 + Z0

  // --- Predictor (pos+neg fused, MFMA) ---
  predictor_kernel<<<(2 * PP) / (4 * 16), 256, 0, stream>>>(pos_src, pos_dst, neg_src, neg_dst,
                                                            pb1, P2, pb2, P3, pb3, d_out);
}

// Round 6
// 487.244 us; speedup vs baseline: 1.5337x; 1.5337x over previous
//
#include <hip/hip_runtime.h>
#include <hip/hip_bf16.h>

typedef unsigned short u16;
typedef unsigned int u32;
typedef short short8v __attribute__((ext_vector_type(8)));
typedef float f32x4 __attribute__((ext_vector_type(4)));

#define NN 50000
#define EE 800000
#define PP 65536
#define NBKT 196      // node buckets of 256: ceil(NN/256)
#define NHB 256       // histogram blocks (edge chunks of 3125)
#define ECH 3125      // edges per histogram block: 256*3125 = EE exactly

// ---- static device workspace. RULE (r3): device-global addresses never cross
// the host/device boundary — kernels resolve them via compile-time IDs.
// RULE (r15): NO cooperative launch / grid.sync on this chip — 512-block cap +
// cross-XCD barrier spin made one fused kernel 2.5x slower than the chain.
__device__ __align__(256) float g_deg_norm[NN];
__device__ __align__(256) int   g_row_ptr[NN + 1];
__device__ __align__(256) int   g_rank[EE];          // intra-node rank
__device__ __align__(256) int   g_bh[NBKT * NHB];    // [bucket][block] counts
__device__ __align__(256) int   g_bbase[NBKT * NHB]; // exclusive scan over blocks
__device__ __align__(256) int   g_btot[NBKT];
__device__ __align__(256) u32   g_ebkt[EE];          // bucket-grouped: src | dlow<<16
__device__ __align__(256) float g_wtmp[EE];          // raw w (f32), bucket-grouped
__device__ __align__(256) float g_w2[EE];            // raw w, CSR order
__device__ __align__(256) u32   g_ecwp[EE];          // final: src(16b) | w_bf16(16b)
__device__ __align__(256) u16   g_X16[NN * 128];     // x bf16, row-major
__device__ __align__(256) u16   g_H1[NN * 128];      // hop outs / 2x Z (layer-3 Horner)
__device__ __align__(256) u16   g_H2[NN * 128];
__device__ __align__(256) u16   g_H3[NN * 128];
__device__ __align__(256) u16   g_Hn0[NN * 128];
__device__ __align__(256) u16   g_Hn1[NN * 128];
__device__ __align__(256) u16   g_Hf16[NN * 64];     // final h (bf16), row-major
__device__ __align__(256) u16   g_Bf1[512 * 128];    // W in MFMA B-fragment order
__device__ __align__(256) u16   g_Bf2[512 * 128];
__device__ __align__(256) u16   g_Bf3[512 * 64];
__device__ __align__(256) u16   g_Pf1[4 * 64 * 8];   // P1 in B-frag order
__device__ int g_f32mode;  // 1 if harness float tensors are float32, 0 if bf16

__device__ __forceinline__ float bf2f(u16 u) {
  union { u32 i; float f; } v;
  v.i = ((u32)u) << 16;
  return v.f;
}
__device__ __forceinline__ u16 f2bf(float f) {
  u32 x = __float_as_uint(f);
  u32 r = (x + 0x7fffu + ((x >> 16) & 1u)) >> 16;  // RNE
  return (u16)r;
}
__device__ __forceinline__ float ldf(const void* p, int i, int m) {
  return m ? ((const float*)p)[i] : bf2f(((const u16*)p)[i]);
}

// buffer IDs: 0 = X16, 3 = Hn0, 4 = Hn1, 5 = H1, 6 = H2, 7 = H3 (stride 128)
template <int ID>
__device__ __forceinline__ u16* sel_buf() {
  if (ID == 0) return g_X16;
  if (ID == 3) return g_Hn0;
  if (ID == 4) return g_Hn1;
  if (ID == 5) return g_H1;
  if (ID == 6) return g_H2;
  return g_H3;
}
template <int ID>
__device__ __forceinline__ u16* sel_bf() {
  if (ID == 1) return g_Bf1;
  if (ID == 2) return g_Bf2;
  return g_Bf3;
}
// width-64 Z/T buffers for layer-3 Horner (carved from H1/H2/H3)
template <int ID>
__device__ __forceinline__ u16* zb() {
  if (ID == 8) return g_H1;                 // Z3
  if (ID == 9) return g_H1 + NN * 64;       // Z2
  if (ID == 10) return g_H2;                // Z1
  if (ID == 11) return g_H2 + NN * 64;      // Z0 (+bias)
  if (ID == 12) return g_H3;                // T ping
  return g_H3 + NN * 64;                    // 13: T pong
}

// -------------------------------------------------------------- dtype probe
__global__ void probe_dtype_kernel(const u16* __restrict__ x) {
  __shared__ int cnt;
  if (threadIdx.x == 0) cnt = 0;
  __syncthreads();
  int c = 0;
  for (int i = threadIdx.x; i < 2048; i += 256) {
    u16 u = x[2 * i];
    int e = (u >> 7) & 0xFF;
    if (e >= 0x8F) c++;
  }
  atomicAdd(&cnt, c);
  __syncthreads();
  if (threadIdx.x == 0) g_f32mode = (cnt > 64) ? 1 : 0;
}

// ---------------- fused prep1: x->bf16 | bucket histogram | W/P convert
// blocks [0,12500): convert x; [12500,12756): LDS bucket-hist of dst>>8;
// [12756,12837): W1/W2/W3/P1 -> B-frag order. (r14-proven)
template <int FOUT>
__device__ __forceinline__ void conv_w_body(const void* W, u16* dstbuf, int t, int m) {
  constexpr int NT = FOUT / 16;
  if (t >= 1024 * NT) return;
  int lane = t & 63;
  int rest = t >> 6;
  int nt = rest % NT;
  int s = (rest / NT) % 4;
  int kc = rest / (NT * 4);
  int kbase = kc * 128 + s * 32 + ((lane >> 4) << 3);
  int n = nt * 16 + (lane & 15);
  u16* dst = dstbuf + (size_t)t * 8;
#pragma unroll
  for (int j = 0; j < 8; ++j) dst[j] = f2bf(ldf(W, (kbase + j) * FOUT + n, m));
}
__global__ void prep1_kernel(const void* __restrict__ x, const int* __restrict__ dst,
                             const void* __restrict__ W1, const void* __restrict__ W2,
                             const void* __restrict__ W3, const void* __restrict__ P1) {
  __shared__ int lhist[NBKT];
  int b = blockIdx.x, tid = threadIdx.x;
  int m = g_f32mode;
  if (b < 12500) {
    int i = b * 256 + tid;  // u32-pair index, exact: 12500*256 = NN*64
    u32 lo = f2bf(ldf(x, 2 * i, m));
    u32 hi = f2bf(ldf(x, 2 * i + 1, m));
    ((u32*)g_X16)[i] = lo | (hi << 16);
  } else if (b < 12500 + NHB) {
    int hb = b - 12500;
    for (int i = tid; i < NBKT; i += 256) lhist[i] = 0;
    __syncthreads();
    int base = hb * ECH;
    for (int i = tid; i < ECH; i += 256) atomicAdd(&lhist[dst[base + i] >> 8], 1);
    __syncthreads();
    if (tid < NBKT) g_bh[tid * NHB + hb] = lhist[tid];
  } else {
    int wb = b - (12500 + NHB);
    if (wb < 32) {
      conv_w_body<128>(W1, g_Bf1, wb * 256 + tid, m);
    } else if (wb < 64) {
      conv_w_body<128>(W2, g_Bf2, (wb - 32) * 256 + tid, m);
    } else if (wb < 80) {
      conv_w_body<64>(W3, g_Bf3, (wb - 64) * 256 + tid, m);
    } else {
      int f = tid >> 6, lane = tid & 63;
      int ks = f >> 1, nt = f & 1;
      int quad = lane >> 4, arow = lane & 15;
#pragma unroll
      for (int j = 0; j < 8; ++j)
        g_Pf1[(size_t)tid * 8 + j] =
            f2bf(ldf(P1, (ks * 32 + quad * 8 + j) * 32 + nt * 16 + arow, m));
    }
  }
}

// ------------------------------------- S2: per-bucket exclusive scan over blocks
__global__ __launch_bounds__(256) void bucket_scan_kernel() {
  __shared__ int ws[4];
  int g = blockIdx.x, t = threadIdx.x;
  int v = g_bh[g * NHB + t];
  int x = v;
#pragma unroll
  for (int off = 1; off < 64; off <<= 1) {
    int y = __shfl_up(x, off, 64);
    if ((t & 63) >= off) x += y;
  }
  if ((t & 63) == 63) ws[t >> 6] = x;
  __syncthreads();
  int wp = 0;
  if (t >= 64) wp += ws[0];
  if (t >= 128) wp += ws[1];
  if (t >= 192) wp += ws[2];
  g_bbase[g * NHB + t] = wp + x - v;  // exclusive within bucket, block order
  if (t == 255) g_btot[g] = wp + x;
}

// --- local bucket-start scan helper: exclusive scan of g_btot into sb[] (LDS)
__device__ __forceinline__ void local_bstart(int* sb, int* ws, int tid) {
  int v = (tid < NBKT) ? g_btot[tid] : 0;
  int x = v;
#pragma unroll
  for (int off = 1; off < 64; off <<= 1) {
    int y = __shfl_up(x, off, 64);
    if ((tid & 63) >= off) x += y;
  }
  if ((tid & 63) == 63) ws[tid >> 6] = x;
  __syncthreads();
  int wp = 0;
  if (tid >= 64) wp += ws[0];
  if (tid >= 128) wp += ws[1];
  if (tid >= 192) wp += ws[2];
  if (tid < NBKT) sb[tid] = wp + x - v;
  if (tid == 0) sb[NBKT] = EE;
  __syncthreads();
}

// ---------------------------- S4: scatter edges into bucket-grouped order
// LDS-atomic local rank per bucket (order within bucket irrelevant: row order
// doesn't affect a segment sum). No global atomics. Computes bucket starts
// locally from g_btot (saves the bstart_scan launch).
__global__ __launch_bounds__(256) void scatter_bucket_kernel(const int* __restrict__ src,
                                                             const int* __restrict__ dst,
                                                             const void* __restrict__ w_edge) {
  __shared__ int sb[NBKT + 1];
  __shared__ int ws[4];
  __shared__ int lhist[NBKT];
  __shared__ int lbase[NBKT];
  int m = g_f32mode;
  int b = blockIdx.x, tid = threadIdx.x;
  local_bstart(sb, ws, tid);
  for (int i = tid; i < NBKT; i += 256) {
    lhist[i] = 0;
    lbase[i] = sb[i] + g_bbase[i * NHB + b];
  }
  __syncthreads();
  int base = b * ECH;
  for (int i = tid; i < ECH; i += 256) {
    int e = base + i;
    int d = dst[e];
    int s = src[e];
    float w = ldf(w_edge, e, m);
    int bkt = d >> 8;
    int r = atomicAdd(&lhist[bkt], 1);
    int pos = lbase[bkt] + r;
    g_ebkt[pos] = (u32)s | ((u32)(d & 255) << 16);
    g_wtmp[pos] = w;
  }
}

// ------------- S5: per-bucket CSR finalize: 256-bin LDS hist -> row_ptr,
// deg_norm, and in-bucket scatter to exact per-node segments.
__global__ __launch_bounds__(256) void csr_finalize_kernel() {
  __shared__ int sb[NBKT + 1];
  __shared__ int ws[4];
  __shared__ int hist[256];
  __shared__ int loff[256];
  int g = blockIdx.x, t = threadIdx.x;
  local_bstart(sb, ws, t);
  int bs = sb[g], be = sb[g + 1];
  hist[t] = 0;
  __syncthreads();
  for (int i = bs + t; i < be; i += 256) {
    int dlow = (g_ebkt[i] >> 16) & 0xFF;
    g_rank[i] = atomicAdd(&hist[dlow], 1);
  }
  __syncthreads();
  int v = hist[t];
  int x = v;
#pragma unroll
  for (int off = 1; off < 64; off <<= 1) {
    int y = __shfl_up(x, off, 64);
    if ((t & 63) >= off) x += y;
  }
  if ((t & 63) == 63) ws[t >> 6] = x;
  __syncthreads();
  int wp = 0;
  if (t >= 64) wp += ws[0];
  if (t >= 128) wp += ws[1];
  if (t >= 192) wp += ws[2];
  int excl = wp + x - v;
  loff[t] = excl;
  int node = g * 256 + t;
  if (node < NN) {
    g_row_ptr[node] = bs + excl;
    g_deg_norm[node] = rsqrtf((float)(v > 0 ? v : 1));
  }
  if (g == NBKT - 1 && t == 0) g_row_ptr[NN] = EE;
  __syncthreads();
  for (int i = bs + t; i < be; i += 256) {
    u32 p = g_ebkt[i];
    int dlow = (p >> 16) & 0xFF;
    int pos = bs + loff[dlow] + g_rank[i];
    g_ecwp[pos] = p;       // src in low 16; w field written by hop1 (FINW)
    g_w2[pos] = g_wtmp[i];
  }
}

// --------------------------------------------------------- width-128 hop
// out[n][f] = deg_norm[n] * sum_e w[e] * in[col[e]][f]
// One wave per node. Lane = (edge-group g=lane>>4, feature-block q=lane&15).
// FINW (layer-1 hop1 only): w = g_w2[e] * deg_norm[src] in f32; finalized
// bf16-packed edge written back for the 8 later hops (replaces wfinal kernel;
// own-segment writes -> race-free; replay-safe: FINW never reads the w field).
template <int IN_ID, int OUT_ID, bool FINW>
__global__ __launch_bounds__(256) void hop_kernel() {
  int wv = __builtin_amdgcn_readfirstlane(threadIdx.x >> 6);  // wave-uniform -> SGPR
  int n = blockIdx.x * 4 + wv;
  if (n >= NN) return;
  int lane = threadIdx.x & 63;
  int g = lane >> 4;   // edge group 0..3
  int q = lane & 15;   // features q*8 .. q*8+7
  const u16* inf = sel_buf<IN_ID>() + q * 8;
  int beg = g_row_ptr[n], end = g_row_ptr[n + 1];
  float a0[8], a1[8];
#pragma unroll
  for (int j = 0; j < 8; ++j) { a0[j] = 0.f; a1[j] = 0.f; }
  int e = beg;
  for (; e + 16 <= end; e += 16) {
    u32 p0 = g_ecwp[e + g];
    u32 p1 = g_ecwp[e + 4 + g];
    u32 p2 = g_ecwp[e + 8 + g];
    u32 p3 = g_ecwp[e + 12 + g];
    float wA, wB, wC, wD;
    if (FINW) {
      float r0 = g_w2[e + g], r1 = g_w2[e + 4 + g], r2 = g_w2[e + 8 + g], r3 = g_w2[e + 12 + g];
      wA = r0 * g_deg_norm[p0 & 0xFFFFu];
      wB = r1 * g_deg_norm[p1 & 0xFFFFu];
      wC = r2 * g_deg_norm[p2 & 0xFFFFu];
      wD = r3 * g_deg_norm[p3 & 0xFFFFu];
    } else {
      wA = bf2f((u16)(p0 >> 16));
      wB = bf2f((u16)(p1 >> 16));
      wC = bf2f((u16)(p2 >> 16));
      wD = bf2f((u16)(p3 >> 16));
    }
    short8v u0 = *(const short8v*)(inf + (p0 & 0xFFFFu) * 128);
    short8v u1 = *(const short8v*)(inf + (p1 & 0xFFFFu) * 128);
    short8v u2 = *(const short8v*)(inf + (p2 & 0xFFFFu) * 128);
    short8v u3 = *(const short8v*)(inf + (p3 & 0xFFFFu) * 128);
#pragma unroll
    for (int j = 0; j < 8; ++j) {
      a0[j] += wA * bf2f((u16)u0[j]);
      a1[j] += wB * bf2f((u16)u1[j]);
      a0[j] += wC * bf2f((u16)u2[j]);
      a1[j] += wD * bf2f((u16)u3[j]);
    }
    if (FINW && q == 0) {
      g_ecwp[e + g]      = (p0 & 0xFFFFu) | ((u32)f2bf(wA) << 16);
      g_ecwp[e + 4 + g]  = (p1 & 0xFFFFu) | ((u32)f2bf(wB) << 16);
      g_ecwp[e + 8 + g]  = (p2 & 0xFFFFu) | ((u32)f2bf(wC) << 16);
      g_ecwp[e + 12 + g] = (p3 & 0xFFFFu) | ((u32)f2bf(wD) << 16);
    }
  }
  for (; e + 8 <= end; e += 8) {
    u32 p0 = g_ecwp[e + g];
    u32 p1 = g_ecwp[e + 4 + g];
    float wA, wB;
    if (FINW) {
      wA = g_w2[e + g] * g_deg_norm[p0 & 0xFFFFu];
      wB = g_w2[e + 4 + g] * g_deg_norm[p1 & 0xFFFFu];
    } else {
      wA = bf2f((u16)(p0 >> 16));
      wB = bf2f((u16)(p1 >> 16));
    }
    short8v u0 = *(const short8v*)(inf + (p0 & 0xFFFFu) * 128);
    short8v u1 = *(const short8v*)(inf + (p1 & 0xFFFFu) * 128);
#pragma unroll
    for (int j = 0; j < 8; ++j) {
      a0[j] += wA * bf2f((u16)u0[j]);
      a1[j] += wB * bf2f((u16)u1[j]);
    }
    if (FINW && q == 0) {
      g_ecwp[e + g]     = (p0 & 0xFFFFu) | ((u32)f2bf(wA) << 16);
      g_ecwp[e + 4 + g] = (p1 & 0xFFFFu) | ((u32)f2bf(wB) << 16);
    }
  }
  for (; e < end; e += 4) {  // masked tail, <=7 left -> <=2 iterations
    if (e + g < end) {
      u32 p = g_ecwp[e + g];
      float w;
      if (FINW) w = g_w2[e + g] * g_deg_norm[p & 0xFFFFu];
      else      w = bf2f((u16)(p >> 16));
      short8v u = *(const short8v*)(inf + (p & 0xFFFFu) * 128);
#pragma unroll
      for (int j = 0; j < 8; ++j) a0[j] += w * bf2f((u16)u[j]);
      if (FINW && q == 0) g_ecwp[e + g] = (p & 0xFFFFu) | ((u32)f2bf(w) << 16);
    }
  }
  float s[8];
#pragma unroll
  for (int j = 0; j < 8; ++j) {
    float v = a0[j] + a1[j];
    v += __shfl_xor(v, 16, 64);
    v += __shfl_xor(v, 32, 64);
    s[j] = v;  // every lane now has totals for features q*8+j
  }
  float dn = g_deg_norm[n];
  // group g writes the u32 covering features q*8+2g, q*8+2g+1 -> 256B coalesced
  u32 outv = (u32)f2bf(s[2 * g] * dn) | ((u32)f2bf(s[2 * g + 1] * dn) << 16);
  *(u32*)(sel_buf<OUT_ID>() + n * 128 + q * 8 + 2 * g) = outv;
}

// ------------------------------------------------- width-64 hop with addend
// T_out[n] = deg_norm[n] * (A T_in)[n] + Add[n]   (layer-3 Horner step)
template <int IN_ID, int ADD_ID, int OUT_ID, bool FINAL>
__global__ __launch_bounds__(256) void hop64_kernel(void* __restrict__ outp) {
  int wv = __builtin_amdgcn_readfirstlane(threadIdx.x >> 6);
  int n = blockIdx.x * 4 + wv;
  if (n >= NN) return;
  int lane = threadIdx.x & 63;
  int g = lane >> 3;  // edge group 0..7
  int q = lane & 7;   // features q*8 .. q*8+7
  const u16* inf = zb<IN_ID>() + q * 8;
  int beg = g_row_ptr[n], end = g_row_ptr[n + 1];
  float a0[8], a1[8];
#pragma unroll
  for (int j = 0; j < 8; ++j) { a0[j] = 0.f; a1[j] = 0.f; }
  int e = beg;
  for (; e + 16 <= end; e += 16) {
    u32 p0 = g_ecwp[e + g];
    u32 p1 = g_ecwp[e + 8 + g];
    short8v u0 = *(const short8v*)(inf + (p0 & 0xFFFFu) * 64);
    short8v u1 = *(const short8v*)(inf + (p1 & 0xFFFFu) * 64);
    float w0 = bf2f((u16)(p0 >> 16));
    float w1 = bf2f((u16)(p1 >> 16));
#pragma unroll
    for (int j = 0; j < 8; ++j) {
      a0[j] += w0 * bf2f((u16)u0[j]);
      a1[j] += w1 * bf2f((u16)u1[j]);
    }
  }
  for (; e + 8 <= end; e += 8) {
    u32 p = g_ecwp[e + g];
    short8v u = *(const short8v*)(inf + (p & 0xFFFFu) * 64);
    float w = bf2f((u16)(p >> 16));
#pragma unroll
    for (int j = 0; j < 8; ++j) a0[j] += w * bf2f((u16)u[j]);
  }
  if (e < end) {  // masked tail, <=7 left, 8 groups -> one iteration
    if (e + g < end) {
      u32 p = g_ecwp[e + g];
      short8v u = *(const short8v*)(inf + (p & 0xFFFFu) * 64);
      float w = bf2f((u16)(p >> 16));
#pragma unroll
      for (int j = 0; j < 8; ++j) a0[j] += w * bf2f((u16)u[j]);
    }
  }
  float s[8];
#pragma unroll
  for (int j = 0; j < 8; ++j) {
    float v = a0[j] + a1[j];
    v += __shfl_xor(v, 8, 64);
    v += __shfl_xor(v, 16, 64);
    v += __shfl_xor(v, 32, 64);
    s[j] = v;
  }
  float dn = g_deg_norm[n];
  if (g < 4) {  // groups 0..3 write the 128-B output row
    int ci = n * 64 + q * 8 + 2 * g;
    u32 ad = *(const u32*)(zb<ADD_ID>() + ci);
    float r0 = s[2 * g] * dn + bf2f((u16)ad);
    float r1 = s[2 * g + 1] * dn + bf2f((u16)(ad >> 16));
    if (!FINAL) {
      *(u32*)(zb<OUT_ID>() + ci) = (u32)f2bf(r0) | ((u32)f2bf(r1) << 16);
    } else {
      *(u32*)(g_Hf16 + ci) = (u32)f2bf(r0) | ((u32)f2bf(r1) << 16);
      if (g_f32mode) {
        ((float*)outp)[2 * PP + ci] = r0;
        ((float*)outp)[2 * PP + ci + 1] = r1;
      } else {
        ((u32*)((u16*)outp + 2 * PP))[ci >> 1] = (u32)f2bf(r0) | ((u32)f2bf(r1) << 16);
      }
    }
  }
}

// -------------------------------------------------- MFMA GEMM (FOUT=128)
// C(M x 128) = [f0 | H1 | H2 | H3] (Mx512, row-major) @ B + bias, ReLU.
template <int A0_ID, int C_ID, int BF_ID>
__global__ __launch_bounds__(256) void gemm_kernel(const void* __restrict__ bias) {
  constexpr int NT = 8;
  const u16* Bf = sel_bf<BF_ID>();
  int tid = threadIdx.x;
  int lane = tid & 63, wv = tid >> 6;
  int quad = lane >> 4, arow = lane & 15;
  int mbase = blockIdx.x * 64 + wv * 16;
  if (mbase >= NN) return;  // no barriers -> safe (NN % 16 == 0)
  int row0 = mbase + arow;

  f32x4 acc[NT];
#pragma unroll
  for (int nt = 0; nt < NT; ++nt) acc[nt] = (f32x4){0.f, 0.f, 0.f, 0.f};

#pragma unroll
  for (int kc = 0; kc < 4; ++kc) {
    const u16* base = (kc == 0) ? sel_buf<A0_ID>() : (kc == 1) ? g_H1 : (kc == 2) ? g_H2 : g_H3;
#pragma unroll
    for (int s = 0; s < 4; ++s) {
      int ko = s * 32 + quad * 8;
      short8v av = *(const short8v*)(base + row0 * 128 + ko);
      const u16* bp = Bf + (size_t)(((kc * 4 + s) * NT) * 64 + lane) * 8;
#pragma unroll
      for (int nt = 0; nt < NT; ++nt) {
        short8v b = *(const short8v*)(bp + nt * 64 * 8);
        acc[nt] = __builtin_amdgcn_mfma_f32_16x16x32_bf16(av, b, acc[nt], 0, 0, 0);
      }
    }
  }

  int m = g_f32mode;
  float bn[NT];
#pragma unroll
  for (int nt = 0; nt < NT; ++nt) bn[nt] = ldf(bias, nt * 16 + arow, m);
#pragma unroll
  for (int i = 0; i < 4; ++i) {
    int row = mbase + quad * 4 + i;  // C/D: col=lane&15, row=quad*4+reg
#pragma unroll
    for (int nt = 0; nt < NT; ++nt) {
      float v = acc[nt][i] + bn[nt];
      v = v > 0.f ? v : 0.f;  // ReLU (layers 1,2 only)
      sel_buf<C_ID>()[row * 128 + nt * 16 + arow] = f2bf(v);
    }
  }
}

// --------------------- fused small GEMM: Z_k = Hn1 @ W3[kc] for kc=0..3
// (r13-proven) One pass over Hn1 computes all four width-64 Z buffers.
__global__ __launch_bounds__(256) void gemm64_all_kernel(const void* __restrict__ bias) {
  int tid = threadIdx.x;
  int lane = tid & 63, wv = tid >> 6;
  int quad = lane >> 4, arow = lane & 15;
  int mbase = blockIdx.x * 64 + wv * 16;
  if (mbase >= NN) return;
  int row0 = mbase + arow;

  f32x4 acc[4][4];  // [kc][nt]
#pragma unroll
  for (int kc = 0; kc < 4; ++kc)
#pragma unroll
    for (int nt = 0; nt < 4; ++nt) acc[kc][nt] = (f32x4){0.f, 0.f, 0.f, 0.f};

#pragma unroll
  for (int s = 0; s < 4; ++s) {
    int ko = s * 32 + quad * 8;
    short8v av = *(const short8v*)(g_Hn1 + row0 * 128 + ko);
#pragma unroll
    for (int kc = 0; kc < 4; ++kc) {
      const u16* bp = g_Bf3 + (size_t)(((kc * 4 + s) * 4) * 64 + lane) * 8;
#pragma unroll
      for (int nt = 0; nt < 4; ++nt) {
        short8v b = *(const short8v*)(bp + nt * 64 * 8);
        acc[kc][nt] = __builtin_amdgcn_mfma_f32_16x16x32_bf16(av, b, acc[kc][nt], 0, 0, 0);
      }
    }
  }

  int m = g_f32mode;
  float bn[4];
#pragma unroll
  for (int nt = 0; nt < 4; ++nt) bn[nt] = ldf(bias, nt * 16 + arow, m);
#pragma unroll
  for (int kc = 0; kc < 4; ++kc) {
    u16* Z = (kc == 0) ? zb<11>() : (kc == 1) ? zb<10>() : (kc == 2) ? zb<9>() : zb<8>();
#pragma unroll
    for (int i = 0; i < 4; ++i) {
      int row = mbase + quad * 4 + i;
#pragma unroll
      for (int nt = 0; nt < 4; ++nt) {
        float v = acc[kc][nt][i] + (kc == 0 ? bn[nt] : 0.f);
        Z[row * 64 + nt * 16 + arow] = f2bf(v);
      }
    }
  }
}

// ------------------------------------------------------------------ predictor
__global__ __launch_bounds__(256) void predictor_kernel(
    const int* __restrict__ pos_src, const int* __restrict__ pos_dst,
    const int* __restrict__ neg_src, const int* __restrict__ neg_dst,
    const void* __restrict__ pb1, const void* __restrict__ P2,
    const void* __restrict__ pb2, const void* __restrict__ P3, const void* __restrict__ pb3,
    void* __restrict__ out) {
  __shared__ float sP2[32 * 16];
  __shared__ float sb1[32], sb2[16], sP3[16];
  __shared__ float sb3;
  __shared__ float zt[4][16][33];
  int m = g_f32mode;
  int tid = threadIdx.x;
  for (int i = tid; i < 512; i += 256) sP2[i] = ldf(P2, i, m);
  if (tid < 32) sb1[tid] = ldf(pb1, tid, m);
  if (tid < 16) sb2[tid] = ldf(pb2, tid, m);
  if (tid < 16) sP3[tid] = ldf(P3, tid, m);
  if (tid == 0) sb3 = ldf(pb3, 0, m);
  __syncthreads();

  int wv = tid >> 6, lane = tid & 63;
  int quad = lane >> 4, arow = lane & 15;
  int base = (blockIdx.x * 4 + wv) * 16;
  int idx = base + arow;
  int s, d;
  if (idx < PP) { s = pos_src[idx]; d = pos_dst[idx]; }  // PP%16==0 -> wave-uniform
  else          { s = neg_src[idx - PP]; d = neg_dst[idx - PP]; }

  const u16* hs = g_Hf16 + s * 64 + quad * 8;
  const u16* hd = g_Hf16 + d * 64 + quad * 8;
  short8v zf[2];
#pragma unroll
  for (int ks = 0; ks < 2; ++ks) {
    short8v a = *(const short8v*)(hs + ks * 32);
    short8v b = *(const short8v*)(hd + ks * 32);
#pragma unroll
    for (int j = 0; j < 8; ++j)
      ((u16*)&zf[ks])[j] = f2bf(bf2f((u16)a[j]) * bf2f((u16)b[j]));
  }
  f32x4 acc[2];
  acc[0] = (f32x4){0.f, 0.f, 0.f, 0.f};
  acc[1] = (f32x4){0.f, 0.f, 0.f, 0.f};
#pragma unroll
  for (int ks = 0; ks < 2; ++ks) {
#pragma unroll
    for (int nt = 0; nt < 2; ++nt) {
      short8v bfr = *(const short8v*)(g_Pf1 + (size_t)((ks * 2 + nt) * 64 + lane) * 8);
      acc[nt] = __builtin_amdgcn_mfma_f32_16x16x32_bf16(zf[ks], bfr, acc[nt], 0, 0, 0);
    }
  }
#pragma unroll
  for (int nt = 0; nt < 2; ++nt) {
    float bn = sb1[nt * 16 + arow];
#pragma unroll
    for (int i = 0; i < 4; ++i) {
      float v = acc[nt][i] + bn;
      zt[wv][quad * 4 + i][nt * 16 + arow] = v > 0.f ? v : 0.2f * v;
    }
  }
  __syncthreads();
  float z2[4];
#pragma unroll
  for (int jj = 0; jj < 4; ++jj) z2[jj] = sb2[quad * 4 + jj];
  const float* zrow = &zt[wv][arow][0];
#pragma unroll
  for (int c = 0; c < 32; ++c) {
    float zc = zrow[c];
#pragma unroll
    for (int jj = 0; jj < 4; ++jj) z2[jj] += zc * sP2[c * 16 + quad * 4 + jj];
  }
  float o = 0.f;
#pragma unroll
  for (int jj = 0; jj < 4; ++jj) {
    float v = z2[jj] > 0.f ? z2[jj] : 0.2f * z2[jj];
    o += v * sP3[quad * 4 + jj];
  }
  o += __shfl_xor(o, 16, 64);
  o += __shfl_xor(o, 32, 64);
  o += sb3;
  if (quad == 0) {
    if (m) ((float*)out)[idx] = o;
    else   ((u16*)out)[idx] = f2bf(o);
  }
}

// ------------------------------------------------------------------- launch
extern "C" void kernel_launch(void* const* d_in, const int* in_sizes, int n_in,
                              void* d_out, int out_size, void* d_ws, size_t ws_size,
                              hipStream_t stream) {
  const u16* x       = (const u16*)d_in[0];
  const int* src     = (const int*)d_in[1];
  const int* dst     = (const int*)d_in[2];
  const void* w_edge = d_in[3];
  const int* pos_src = (const int*)d_in[4];
  const int* pos_dst = (const int*)d_in[5];
  const int* neg_src = (const int*)d_in[6];
  const int* neg_dst = (const int*)d_in[7];
  const void* W1 = d_in[8];
  const void* b1 = d_in[9];
  const void* W2 = d_in[10];
  const void* b2 = d_in[11];
  const void* W3 = d_in[12];
  const void* b3 = d_in[13];
  const void* P1  = d_in[14];
  const void* pb1 = d_in[15];
  const void* P2  = d_in[16];
  const void* pb2 = d_in[17];
  const void* P3  = d_in[18];
  const void* pb3 = d_in[19];
  (void)d_ws; (void)ws_size; (void)in_sizes; (void)n_in; (void)out_size;

  // --- probe + atomic-free CSR build (separate launches: r15 lesson) ---
  probe_dtype_kernel<<<1, 256, 0, stream>>>(x);
  prep1_kernel<<<12500 + NHB + 81, 256, 0, stream>>>(x, dst, W1, W2, W3, P1);
  bucket_scan_kernel<<<NBKT, 256, 0, stream>>>();
  scatter_bucket_kernel<<<NHB, 256, 0, stream>>>(src, dst, w_edge);
  csr_finalize_kernel<<<NBKT, 256, 0, stream>>>();

  int gHop = (NN + 3) / 4;
  int gGemm = (NN + 63) / 64;

  // --- Layer 1: f0 = x(bf16); hop1 finalizes edge weights (FINW) ---
  hop_kernel<0, 5, true><<<gHop, 256, 0, stream>>>();
  hop_kernel<5, 6, false><<<gHop, 256, 0, stream>>>();
  hop_kernel<6, 7, false><<<gHop, 256, 0, stream>>>();
  gemm_kernel<0, 3, 1><<<gGemm, 256, 0, stream>>>(b1);

  // --- Layer 2: f0 = Hn0 ---
  hop_kernel<3, 5, false><<<gHop, 256, 0, stream>>>();
  hop_kernel<5, 6, false><<<gHop, 256, 0, stream>>>();
  hop_kernel<6, 7, false><<<gHop, 256, 0, stream>>>();
  gemm_kernel<3, 4, 2><<<gGemm, 256, 0, stream>>>(b2);

  // --- Layer 3 (Horner): out = Z0+b3 + A(Z1 + A(Z2 + A Z3)), Z_k = Hn1@W3_k ---
  gemm64_all_kernel<<<gGemm, 256, 0, stream>>>(b3);  // Z3,Z2,Z1,Z0+b3 fused
  hop64_kernel<8, 9, 12, false><<<gHop, 256, 0, stream>>>(nullptr);   // T1 = A Z3 + Z2
  hop64_kernel<12, 10, 13, false><<<gHop, 256, 0, stream>>>(nullptr); // T2 = A T1 + Z1
  hop64_kernel<13, 11, 12, true><<<gHop, 256, 0, stream>>>(d_out);    // h = A T2 + Z0

  // --- Predictor (pos+neg fused, MFMA) ---
  predictor_kernel<<<(2 * PP) / (4 * 16), 256, 0, stream>>>(pos_src, pos_dst, neg_src, neg_dst,
                                                            pb1, P2, pb2, P3, pb3, d_out);
}

// Round 7
// 484.532 us; speedup vs baseline: 1.5423x; 1.0056x over previous
//
#include <hip/hip_runtime.h>
#include <hip/hip_bf16.h>

typedef unsigned short u16;
typedef unsigned int u32;
typedef short short8v __attribute__((ext_vector_type(8)));
typedef float f32x4 __attribute__((ext_vector_type(4)));

#define NN 50000
#define EE 800000
#define PP 65536
#define NBKT 196      // node buckets of 256: ceil(NN/256)
#define NHB 256       // histogram blocks (edge chunks of 3125)
#define ECH 3125      // edges per histogram block: 256*3125 = EE exactly

// ---- static device workspace. RULE (r3): device-global addresses never cross
// the host/device boundary — kernels resolve them via compile-time IDs.
// RULE (r15): NO cooperative launch / grid.sync on this chip — 512-block cap +
// cross-XCD barrier spin made one fused kernel 2.5x slower than the chain.
__device__ __align__(256) float g_deg_norm[NN];
__device__ __align__(256) int   g_row_ptr[NN + 1];
__device__ __align__(256) int   g_rank[EE];          // intra-node rank
__device__ __align__(256) int   g_bh[NBKT * NHB];    // [bucket][block] counts
__device__ __align__(256) int   g_bbase[NBKT * NHB]; // exclusive scan over blocks
__device__ __align__(256) int   g_btot[NBKT];
__device__ __align__(256) u32   g_ebkt[EE];          // bucket-grouped: src | dlow<<16
__device__ __align__(256) float g_wtmp[EE];          // raw w (f32), bucket-grouped
__device__ __align__(256) float g_w2[EE];            // raw w, CSR order
__device__ __align__(256) u32   g_ecwp[EE];          // final: src(16b) | w_bf16(16b)
__device__ __align__(256) u16   g_X16[NN * 128];     // x bf16, row-major
__device__ __align__(256) u16   g_H1[NN * 128];      // hop outs / 2x Z (layer-3 Horner)
__device__ __align__(256) u16   g_H2[NN * 128];
__device__ __align__(256) u16   g_H3[NN * 128];
__device__ __align__(256) u16   g_Hn0[NN * 128];
__device__ __align__(256) u16   g_Hn1[NN * 128];
__device__ __align__(256) u16   g_Hf16[NN * 64];     // final h (bf16), row-major
__device__ __align__(256) u16   g_Bf1[512 * 128];    // W in MFMA B-fragment order
__device__ __align__(256) u16   g_Bf2[512 * 128];
__device__ __align__(256) u16   g_Bf3[512 * 64];
__device__ __align__(256) u16   g_Pf1[4 * 64 * 8];   // P1 in B-frag order
__device__ int g_f32mode;  // 1 if harness float tensors are float32, 0 if bf16

__device__ __forceinline__ float bf2f(u16 u) {
  union { u32 i; float f; } v;
  v.i = ((u32)u) << 16;
  return v.f;
}
__device__ __forceinline__ u16 f2bf(float f) {
  u32 x = __float_as_uint(f);
  u32 r = (x + 0x7fffu + ((x >> 16) & 1u)) >> 16;  // RNE
  return (u16)r;
}
__device__ __forceinline__ float ldf(const void* p, int i, int m) {
  return m ? ((const float*)p)[i] : bf2f(((const u16*)p)[i]);
}

// buffer IDs: 0 = X16, 3 = Hn0, 4 = Hn1, 5 = H1, 6 = H2, 7 = H3 (stride 128)
template <int ID>
__device__ __forceinline__ u16* sel_buf() {
  if (ID == 0) return g_X16;
  if (ID == 3) return g_Hn0;
  if (ID == 4) return g_Hn1;
  if (ID == 5) return g_H1;
  if (ID == 6) return g_H2;
  return g_H3;
}
template <int ID>
__device__ __forceinline__ u16* sel_bf() {
  if (ID == 1) return g_Bf1;
  if (ID == 2) return g_Bf2;
  return g_Bf3;
}
// width-64 Z/T buffers for layer-3 Horner (carved from H1/H2/H3)
template <int ID>
__device__ __forceinline__ u16* zb() {
  if (ID == 8) return g_H1;                 // Z3
  if (ID == 9) return g_H1 + NN * 64;       // Z2
  if (ID == 10) return g_H2;                // Z1
  if (ID == 11) return g_H2 + NN * 64;      // Z0 (+bias)
  if (ID == 12) return g_H3;                // T ping
  return g_H3 + NN * 64;                    // 13: T pong
}

// -------------------------------------------------------------- dtype probe
__global__ void probe_dtype_kernel(const u16* __restrict__ x) {
  __shared__ int cnt;
  if (threadIdx.x == 0) cnt = 0;
  __syncthreads();
  int c = 0;
  for (int i = threadIdx.x; i < 2048; i += 256) {
    u16 u = x[2 * i];
    int e = (u >> 7) & 0xFF;
    if (e >= 0x8F) c++;
  }
  atomicAdd(&cnt, c);
  __syncthreads();
  if (threadIdx.x == 0) g_f32mode = (cnt > 64) ? 1 : 0;
}

// ---------------- fused prep1: x->bf16 | bucket histogram | W/P convert
// blocks [0,12500): convert x; [12500,12756): LDS bucket-hist of dst>>8;
// [12756,12837): W1/W2/W3/P1 -> B-frag order. (r14-proven)
template <int FOUT>
__device__ __forceinline__ void conv_w_body(const void* W, u16* dstbuf, int t, int m) {
  constexpr int NT = FOUT / 16;
  if (t >= 1024 * NT) return;
  int lane = t & 63;
  int rest = t >> 6;
  int nt = rest % NT;
  int s = (rest / NT) % 4;
  int kc = rest / (NT * 4);
  int kbase = kc * 128 + s * 32 + ((lane >> 4) << 3);
  int n = nt * 16 + (lane & 15);
  u16* dst = dstbuf + (size_t)t * 8;
#pragma unroll
  for (int j = 0; j < 8; ++j) dst[j] = f2bf(ldf(W, (kbase + j) * FOUT + n, m));
}
__global__ void prep1_kernel(const void* __restrict__ x, const int* __restrict__ dst,
                             const void* __restrict__ W1, const void* __restrict__ W2,
                             const void* __restrict__ W3, const void* __restrict__ P1) {
  __shared__ int lhist[NBKT];
  int b = blockIdx.x, tid = threadIdx.x;
  int m = g_f32mode;
  if (b < 12500) {
    int i = b * 256 + tid;  // u32-pair index, exact: 12500*256 = NN*64
    u32 lo = f2bf(ldf(x, 2 * i, m));
    u32 hi = f2bf(ldf(x, 2 * i + 1, m));
    ((u32*)g_X16)[i] = lo | (hi << 16);
  } else if (b < 12500 + NHB) {
    int hb = b - 12500;
    for (int i = tid; i < NBKT; i += 256) lhist[i] = 0;
    __syncthreads();
    int base = hb * ECH;
    for (int i = tid; i < ECH; i += 256) atomicAdd(&lhist[dst[base + i] >> 8], 1);
    __syncthreads();
    if (tid < NBKT) g_bh[tid * NHB + hb] = lhist[tid];
  } else {
    int wb = b - (12500 + NHB);
    if (wb < 32) {
      conv_w_body<128>(W1, g_Bf1, wb * 256 + tid, m);
    } else if (wb < 64) {
      conv_w_body<128>(W2, g_Bf2, (wb - 32) * 256 + tid, m);
    } else if (wb < 80) {
      conv_w_body<64>(W3, g_Bf3, (wb - 64) * 256 + tid, m);
    } else {
      int f = tid >> 6, lane = tid & 63;
      int ks = f >> 1, nt = f & 1;
      int quad = lane >> 4, arow = lane & 15;
#pragma unroll
      for (int j = 0; j < 8; ++j)
        g_Pf1[(size_t)tid * 8 + j] =
            f2bf(ldf(P1, (ks * 32 + quad * 8 + j) * 32 + nt * 16 + arow, m));
    }
  }
}

// ------------------------------------- S2: per-bucket exclusive scan over blocks
__global__ __launch_bounds__(256) void bucket_scan_kernel() {
  __shared__ int ws[4];
  int g = blockIdx.x, t = threadIdx.x;
  int v = g_bh[g * NHB + t];
  int x = v;
#pragma unroll
  for (int off = 1; off < 64; off <<= 1) {
    int y = __shfl_up(x, off, 64);
    if ((t & 63) >= off) x += y;
  }
  if ((t & 63) == 63) ws[t >> 6] = x;
  __syncthreads();
  int wp = 0;
  if (t >= 64) wp += ws[0];
  if (t >= 128) wp += ws[1];
  if (t >= 192) wp += ws[2];
  g_bbase[g * NHB + t] = wp + x - v;  // exclusive within bucket, block order
  if (t == 255) g_btot[g] = wp + x;
}

// --- local bucket-start scan helper: exclusive scan of g_btot into sb[] (LDS)
__device__ __forceinline__ void local_bstart(int* sb, int* ws, int tid) {
  int v = (tid < NBKT) ? g_btot[tid] : 0;
  int x = v;
#pragma unroll
  for (int off = 1; off < 64; off <<= 1) {
    int y = __shfl_up(x, off, 64);
    if ((tid & 63) >= off) x += y;
  }
  if ((tid & 63) == 63) ws[tid >> 6] = x;
  __syncthreads();
  int wp = 0;
  if (tid >= 64) wp += ws[0];
  if (tid >= 128) wp += ws[1];
  if (tid >= 192) wp += ws[2];
  if (tid < NBKT) sb[tid] = wp + x - v;
  if (tid == 0) sb[NBKT] = EE;
  __syncthreads();
}

// ---------------------------- S4: scatter edges into bucket-grouped order
__global__ __launch_bounds__(256) void scatter_bucket_kernel(const int* __restrict__ src,
                                                             const int* __restrict__ dst,
                                                             const void* __restrict__ w_edge) {
  __shared__ int sb[NBKT + 1];
  __shared__ int ws[4];
  __shared__ int lhist[NBKT];
  __shared__ int lbase[NBKT];
  int m = g_f32mode;
  int b = blockIdx.x, tid = threadIdx.x;
  local_bstart(sb, ws, tid);
  for (int i = tid; i < NBKT; i += 256) {
    lhist[i] = 0;
    lbase[i] = sb[i] + g_bbase[i * NHB + b];
  }
  __syncthreads();
  int base = b * ECH;
  for (int i = tid; i < ECH; i += 256) {
    int e = base + i;
    int d = dst[e];
    int s = src[e];
    float w = ldf(w_edge, e, m);
    int bkt = d >> 8;
    int r = atomicAdd(&lhist[bkt], 1);
    int pos = lbase[bkt] + r;
    g_ebkt[pos] = (u32)s | ((u32)(d & 255) << 16);
    g_wtmp[pos] = w;
  }
}

// ------------- S5: per-bucket CSR finalize: 256-bin LDS hist -> row_ptr,
// deg_norm, and in-bucket scatter to exact per-node segments.
__global__ __launch_bounds__(256) void csr_finalize_kernel() {
  __shared__ int sb[NBKT + 1];
  __shared__ int ws[4];
  __shared__ int hist[256];
  __shared__ int loff[256];
  int g = blockIdx.x, t = threadIdx.x;
  local_bstart(sb, ws, t);
  int bs = sb[g], be = sb[g + 1];
  hist[t] = 0;
  __syncthreads();
  for (int i = bs + t; i < be; i += 256) {
    int dlow = (g_ebkt[i] >> 16) & 0xFF;
    g_rank[i] = atomicAdd(&hist[dlow], 1);
  }
  __syncthreads();
  int v = hist[t];
  int x = v;
#pragma unroll
  for (int off = 1; off < 64; off <<= 1) {
    int y = __shfl_up(x, off, 64);
    if ((t & 63) >= off) x += y;
  }
  if ((t & 63) == 63) ws[t >> 6] = x;
  __syncthreads();
  int wp = 0;
  if (t >= 64) wp += ws[0];
  if (t >= 128) wp += ws[1];
  if (t >= 192) wp += ws[2];
  int excl = wp + x - v;
  loff[t] = excl;
  int node = g * 256 + t;
  if (node < NN) {
    g_row_ptr[node] = bs + excl;
    g_deg_norm[node] = rsqrtf((float)(v > 0 ? v : 1));
  }
  if (g == NBKT - 1 && t == 0) g_row_ptr[NN] = EE;
  __syncthreads();
  for (int i = bs + t; i < be; i += 256) {
    u32 p = g_ebkt[i];
    int dlow = (p >> 16) & 0xFF;
    int pos = bs + loff[dlow] + g_rank[i];
    g_ecwp[pos] = p;       // src in low 16; w field written by hop1 (FINW)
    g_w2[pos] = g_wtmp[i];
  }
}

// --------------------------------------------------------- width-128 hop (r19)
// out[n][f] = deg_norm[n] * sum_e w[e] * in[col[e]][f]
// One wave per node. Lane = (edge-group g=lane>>4, feature-block q=lane&15).
// r19: per-lane packet prefetch. Each 64-edge chunk loads packets+weights into
// registers with ONE coalesced load, then the gather loop has NO dependent
// memory loads — addresses come from __shfl of registers, so gathers pipeline
// across iterations instead of serializing behind packet-load latency.
// FINW (layer-1 hop1): w = g_w2[e]*deg_norm[src] per-lane (f32), finalized
// bf16 edge written back by the OWNING lane (race-free, replay-safe).
template <int IN_ID, int OUT_ID, bool FINW>
__global__ __launch_bounds__(256) void hop_kernel() {
  int wv = __builtin_amdgcn_readfirstlane(threadIdx.x >> 6);  // wave-uniform -> SGPR
  int n = blockIdx.x * 4 + wv;
  if (n >= NN) return;
  int lane = threadIdx.x & 63;
  int g = lane >> 4;   // edge group 0..3
  int q = lane & 15;   // features q*8 .. q*8+7
  const u16* inf = sel_buf<IN_ID>() + q * 8;
  int beg = g_row_ptr[n], end = g_row_ptr[n + 1];
  float a0[8], a1[8];
#pragma unroll
  for (int j = 0; j < 8; ++j) { a0[j] = 0.f; a1[j] = 0.f; }
  for (int c = beg; c < end; c += 64) {
    int rem = end - c;
    if (rem > 64) rem = 64;
    u32 myp = 0;
    float wf = 0.f;
    if (lane < rem) {
      myp = g_ecwp[c + lane];
      if (FINW) {
        wf = g_w2[c + lane] * g_deg_norm[myp & 0xFFFFu];
        g_ecwp[c + lane] = (myp & 0xFFFFu) | ((u32)f2bf(wf) << 16);
      } else {
        wf = bf2f((u16)(myp >> 16));
      }
    }
    int i = 0;
    for (; i + 16 <= rem; i += 16) {
      u32 p0 = __shfl(myp, i + g, 64);
      u32 p1 = __shfl(myp, i + 4 + g, 64);
      u32 p2 = __shfl(myp, i + 8 + g, 64);
      u32 p3 = __shfl(myp, i + 12 + g, 64);
      float w0 = __shfl(wf, i + g, 64);
      float w1 = __shfl(wf, i + 4 + g, 64);
      float w2 = __shfl(wf, i + 8 + g, 64);
      float w3 = __shfl(wf, i + 12 + g, 64);
      short8v u0 = *(const short8v*)(inf + (p0 & 0xFFFFu) * 128);
      short8v u1 = *(const short8v*)(inf + (p1 & 0xFFFFu) * 128);
      short8v u2 = *(const short8v*)(inf + (p2 & 0xFFFFu) * 128);
      short8v u3 = *(const short8v*)(inf + (p3 & 0xFFFFu) * 128);
#pragma unroll
      for (int j = 0; j < 8; ++j) {
        a0[j] += w0 * bf2f((u16)u0[j]);
        a1[j] += w1 * bf2f((u16)u1[j]);
        a0[j] += w2 * bf2f((u16)u2[j]);
        a1[j] += w3 * bf2f((u16)u3[j]);
      }
    }
    for (; i + 4 <= rem; i += 4) {
      u32 p = __shfl(myp, i + g, 64);
      float w = __shfl(wf, i + g, 64);
      short8v u = *(const short8v*)(inf + (p & 0xFFFFu) * 128);
#pragma unroll
      for (int j = 0; j < 8; ++j) a0[j] += w * bf2f((u16)u[j]);
    }
    if (i < rem) {  // tail 1..3 edges: groups g < rem-i take one each
      u32 p = __shfl(myp, i + g, 64);
      float w = __shfl(wf, i + g, 64);
      if (g < rem - i) {
        short8v u = *(const short8v*)(inf + (p & 0xFFFFu) * 128);
#pragma unroll
        for (int j = 0; j < 8; ++j) a0[j] += w * bf2f((u16)u[j]);
      }
    }
  }
  float s[8];
#pragma unroll
  for (int j = 0; j < 8; ++j) {
    float v = a0[j] + a1[j];
    v += __shfl_xor(v, 16, 64);
    v += __shfl_xor(v, 32, 64);
    s[j] = v;  // every lane now has totals for features q*8+j
  }
  float dn = g_deg_norm[n];
  // group g writes the u32 covering features q*8+2g, q*8+2g+1 -> 256B coalesced
  u32 outv = (u32)f2bf(s[2 * g] * dn) | ((u32)f2bf(s[2 * g + 1] * dn) << 16);
  *(u32*)(sel_buf<OUT_ID>() + n * 128 + q * 8 + 2 * g) = outv;
}

// ------------------------------------------------- width-64 hop with addend
// T_out[n] = deg_norm[n] * (A T_in)[n] + Add[n]   (layer-3 Horner step)
// r19: same per-lane packet-prefetch restructure (8 edge-groups of 8 lanes).
template <int IN_ID, int ADD_ID, int OUT_ID, bool FINAL>
__global__ __launch_bounds__(256) void hop64_kernel(void* __restrict__ outp) {
  int wv = __builtin_amdgcn_readfirstlane(threadIdx.x >> 6);
  int n = blockIdx.x * 4 + wv;
  if (n >= NN) return;
  int lane = threadIdx.x & 63;
  int g = lane >> 3;  // edge group 0..7
  int q = lane & 7;   // features q*8 .. q*8+7
  const u16* inf = zb<IN_ID>() + q * 8;
  int beg = g_row_ptr[n], end = g_row_ptr[n + 1];
  float a0[8], a1[8];
#pragma unroll
  for (int j = 0; j < 8; ++j) { a0[j] = 0.f; a1[j] = 0.f; }
  for (int c = beg; c < end; c += 64) {
    int rem = end - c;
    if (rem > 64) rem = 64;
    u32 myp = 0;
    float wf = 0.f;
    if (lane < rem) {
      myp = g_ecwp[c + lane];
      wf = bf2f((u16)(myp >> 16));
    }
    int i = 0;
    for (; i + 16 <= rem; i += 16) {
      u32 p0 = __shfl(myp, i + g, 64);
      u32 p1 = __shfl(myp, i + 8 + g, 64);
      float w0 = __shfl(wf, i + g, 64);
      float w1 = __shfl(wf, i + 8 + g, 64);
      short8v u0 = *(const short8v*)(inf + (p0 & 0xFFFFu) * 64);
      short8v u1 = *(const short8v*)(inf + (p1 & 0xFFFFu) * 64);
#pragma unroll
      for (int j = 0; j < 8; ++j) {
        a0[j] += w0 * bf2f((u16)u0[j]);
        a1[j] += w1 * bf2f((u16)u1[j]);
      }
    }
    for (; i + 8 <= rem; i += 8) {
      u32 p = __shfl(myp, i + g, 64);
      float w = __shfl(wf, i + g, 64);
      short8v u = *(const short8v*)(inf + (p & 0xFFFFu) * 64);
#pragma unroll
      for (int j = 0; j < 8; ++j) a0[j] += w * bf2f((u16)u[j]);
    }
    if (i < rem) {  // tail 1..7 edges: groups g < rem-i take one each
      u32 p = __shfl(myp, i + g, 64);
      float w = __shfl(wf, i + g, 64);
      if (g < rem - i) {
        short8v u = *(const short8v*)(inf + (p & 0xFFFFu) * 64);
#pragma unroll
        for (int j = 0; j < 8; ++j) a0[j] += w * bf2f((u16)u[j]);
      }
    }
  }
  float s[8];
#pragma unroll
  for (int j = 0; j < 8; ++j) {
    float v = a0[j] + a1[j];
    v += __shfl_xor(v, 8, 64);
    v += __shfl_xor(v, 16, 64);
    v += __shfl_xor(v, 32, 64);
    s[j] = v;
  }
  float dn = g_deg_norm[n];
  if (g < 4) {  // groups 0..3 write the 128-B output row
    int ci = n * 64 + q * 8 + 2 * g;
    u32 ad = *(const u32*)(zb<ADD_ID>() + ci);
    float r0 = s[2 * g] * dn + bf2f((u16)ad);
    float r1 = s[2 * g + 1] * dn + bf2f((u16)(ad >> 16));
    if (!FINAL) {
      *(u32*)(zb<OUT_ID>() + ci) = (u32)f2bf(r0) | ((u32)f2bf(r1) << 16);
    } else {
      *(u32*)(g_Hf16 + ci) = (u32)f2bf(r0) | ((u32)f2bf(r1) << 16);
      if (g_f32mode) {
        ((float*)outp)[2 * PP + ci] = r0;
        ((float*)outp)[2 * PP + ci + 1] = r1;
      } else {
        ((u32*)((u16*)outp + 2 * PP))[ci >> 1] = (u32)f2bf(r0) | ((u32)f2bf(r1) << 16);
      }
    }
  }
}

// -------------------------------------------------- MFMA GEMM (FOUT=128)
// C(M x 128) = [f0 | H1 | H2 | H3] (Mx512, row-major) @ B + bias, ReLU.
template <int A0_ID, int C_ID, int BF_ID>
__global__ __launch_bounds__(256) void gemm_kernel(const void* __restrict__ bias) {
  constexpr int NT = 8;
  const u16* Bf = sel_bf<BF_ID>();
  int tid = threadIdx.x;
  int lane = tid & 63, wv = tid >> 6;
  int quad = lane >> 4, arow = lane & 15;
  int mbase = blockIdx.x * 64 + wv * 16;
  if (mbase >= NN) return;  // no barriers -> safe (NN % 16 == 0)
  int row0 = mbase + arow;

  f32x4 acc[NT];
#pragma unroll
  for (int nt = 0; nt < NT; ++nt) acc[nt] = (f32x4){0.f, 0.f, 0.f, 0.f};

#pragma unroll
  for (int kc = 0; kc < 4; ++kc) {
    const u16* base = (kc == 0) ? sel_buf<A0_ID>() : (kc == 1) ? g_H1 : (kc == 2) ? g_H2 : g_H3;
#pragma unroll
    for (int s = 0; s < 4; ++s) {
      int ko = s * 32 + quad * 8;
      short8v av = *(const short8v*)(base + row0 * 128 + ko);
      const u16* bp = Bf + (size_t)(((kc * 4 + s) * NT) * 64 + lane) * 8;
#pragma unroll
      for (int nt = 0; nt < NT; ++nt) {
        short8v b = *(const short8v*)(bp + nt * 64 * 8);
        acc[nt] = __builtin_amdgcn_mfma_f32_16x16x32_bf16(av, b, acc[nt], 0, 0, 0);
      }
    }
  }

  int m = g_f32mode;
  float bn[NT];
#pragma unroll
  for (int nt = 0; nt < NT; ++nt) bn[nt] = ldf(bias, nt * 16 + arow, m);
#pragma unroll
  for (int i = 0; i < 4; ++i) {
    int row = mbase + quad * 4 + i;  // C/D: col=lane&15, row=quad*4+reg
#pragma unroll
    for (int nt = 0; nt < NT; ++nt) {
      float v = acc[nt][i] + bn[nt];
      v = v > 0.f ? v : 0.f;  // ReLU (layers 1,2 only)
      sel_buf<C_ID>()[row * 128 + nt * 16 + arow] = f2bf(v);
    }
  }
}

// --------------------- fused small GEMM: Z_k = Hn1 @ W3[kc] for kc=0..3
// (r13-proven) One pass over Hn1 computes all four width-64 Z buffers.
__global__ __launch_bounds__(256) void gemm64_all_kernel(const void* __restrict__ bias) {
  int tid = threadIdx.x;
  int lane = tid & 63, wv = tid >> 6;
  int quad = lane >> 4, arow = lane & 15;
  int mbase = blockIdx.x * 64 + wv * 16;
  if (mbase >= NN) return;
  int row0 = mbase + arow;

  f32x4 acc[4][4];  // [kc][nt]
#pragma unroll
  for (int kc = 0; kc < 4; ++kc)
#pragma unroll
    for (int nt = 0; nt < 4; ++nt) acc[kc][nt] = (f32x4){0.f, 0.f, 0.f, 0.f};

#pragma unroll
  for (int s = 0; s < 4; ++s) {
    int ko = s * 32 + quad * 8;
    short8v av = *(const short8v*)(g_Hn1 + row0 * 128 + ko);
#pragma unroll
    for (int kc = 0; kc < 4; ++kc) {
      const u16* bp = g_Bf3 + (size_t)(((kc * 4 + s) * 4) * 64 + lane) * 8;
#pragma unroll
      for (int nt = 0; nt < 4; ++nt) {
        short8v b = *(const short8v*)(bp + nt * 64 * 8);
        acc[kc][nt] = __builtin_amdgcn_mfma_f32_16x16x32_bf16(av, b, acc[kc][nt], 0, 0, 0);
      }
    }
  }

  int m = g_f32mode;
  float bn[4];
#pragma unroll
  for (int nt = 0; nt < 4; ++nt) bn[nt] = ldf(bias, nt * 16 + arow, m);
#pragma unroll
  for (int kc = 0; kc < 4; ++kc) {
    u16* Z = (kc == 0) ? zb<11>() : (kc == 1) ? zb<10>() : (kc == 2) ? zb<9>() : zb<8>();
#pragma unroll
    for (int i = 0; i < 4; ++i) {
      int row = mbase + quad * 4 + i;
#pragma unroll
      for (int nt = 0; nt < 4; ++nt) {
        float v = acc[kc][nt][i] + (kc == 0 ? bn[nt] : 0.f);
        Z[row * 64 + nt * 16 + arow] = f2bf(v);
      }
    }
  }
}

// ------------------------------------------------------------------ predictor
__global__ __launch_bounds__(256) void predictor_kernel(
    const int* __restrict__ pos_src, const int* __restrict__ pos_dst,
    const int* __restrict__ neg_src, const int* __restrict__ neg_dst,
    const void* __restrict__ pb1, const void* __restrict__ P2,
    const void* __restrict__ pb2, const void* __restrict__ P3, const void* __restrict__ pb3,
    void* __restrict__ out) {
  __shared__ float sP2[32 * 16];
  __shared__ float sb1[32], sb2[16], sP3[16];
  __shared__ float sb3;
  __shared__ float zt[4][16][33];
  int m = g_f32mode;
  int tid = threadIdx.x;
  for (int i = tid; i < 512; i += 256) sP2[i] = ldf(P2, i, m);
  if (tid < 32) sb1[tid] = ldf(pb1, tid, m);
  if (tid < 16) sb2[tid] = ldf(pb2, tid, m);
  if (tid < 16) sP3[tid] = ldf(P3, tid, m);
  if (tid == 0) sb3 = ldf(pb3, 0, m);
  __syncthreads();

  int wv = tid >> 6, lane = tid & 63;
  int quad = lane >> 4, arow = lane & 15;
  int base = (blockIdx.x * 4 + wv) * 16;
  int idx = base + arow;
  int s, d;
  if (idx < PP) { s = pos_src[idx]; d = pos_dst[idx]; }  // PP%16==0 -> wave-uniform
  else          { s = neg_src[idx - PP]; d = neg_dst[idx - PP]; }

  const u16* hs = g_Hf16 + s * 64 + quad * 8;
  const u16* hd = g_Hf16 + d * 64 + quad * 8;
  short8v zf[2];
#pragma unroll
  for (int ks = 0; ks < 2; ++ks) {
    short8v a = *(const short8v*)(hs + ks * 32);
    short8v b = *(const short8v*)(hd + ks * 32);
#pragma unroll
    for (int j = 0; j < 8; ++j)
      ((u16*)&zf[ks])[j] = f2bf(bf2f((u16)a[j]) * bf2f((u16)b[j]));
  }
  f32x4 acc[2];
  acc[0] = (f32x4){0.f, 0.f, 0.f, 0.f};
  acc[1] = (f32x4){0.f, 0.f, 0.f, 0.f};
#pragma unroll
  for (int ks = 0; ks < 2; ++ks) {
#pragma unroll
    for (int nt = 0; nt < 2; ++nt) {
      short8v bfr = *(const short8v*)(g_Pf1 + (size_t)((ks * 2 + nt) * 64 + lane) * 8);
      acc[nt] = __builtin_amdgcn_mfma_f32_16x16x32_bf16(zf[ks], bfr, acc[nt], 0, 0, 0);
    }
  }
#pragma unroll
  for (int nt = 0; nt < 2; ++nt) {
    float bn = sb1[nt * 16 + arow];
#pragma unroll
    for (int i = 0; i < 4; ++i) {
      float v = acc[nt][i] + bn;
      zt[wv][quad * 4 + i][nt * 16 + arow] = v > 0.f ? v : 0.2f * v;
    }
  }
  __syncthreads();
  float z2[4];
#pragma unroll
  for (int jj = 0; jj < 4; ++jj) z2[jj] = sb2[quad * 4 + jj];
  const float* zrow = &zt[wv][arow][0];
#pragma unroll
  for (int c = 0; c < 32; ++c) {
    float zc = zrow[c];
#pragma unroll
    for (int jj = 0; jj < 4; ++jj) z2[jj] += zc * sP2[c * 16 + quad * 4 + jj];
  }
  float o = 0.f;
#pragma unroll
  for (int jj = 0; jj < 4; ++jj) {
    float v = z2[jj] > 0.f ? z2[jj] : 0.2f * z2[jj];
    o += v * sP3[quad * 4 + jj];
  }
  o += __shfl_xor(o, 16, 64);
  o += __shfl_xor(o, 32, 64);
  o += sb3;
  if (quad == 0) {
    if (m) ((float*)out)[idx] = o;
    else   ((u16*)out)[idx] = f2bf(o);
  }
}

// ------------------------------------------------------------------- launch
extern "C" void kernel_launch(void* const* d_in, const int* in_sizes, int n_in,
                              void* d_out, int out_size, void* d_ws, size_t ws_size,
                              hipStream_t stream) {
  const u16* x       = (const u16*)d_in[0];
  const int* src     = (const int*)d_in[1];
  const int* dst     = (const int*)d_in[2];
  const void* w_edge = d_in[3];
  const int* pos_src = (const int*)d_in[4];
  const int* pos_dst = (const int*)d_in[5];
  const int* neg_src = (const int*)d_in[6];
  const int* neg_dst = (const int*)d_in[7];
  const void* W1 = d_in[8];
  const void* b1 = d_in[9];
  const void* W2 = d_in[10];
  const void* b2 = d_in[11];
  const void* W3 = d_in[12];
  const void* b3 = d_in[13];
  const void* P1  = d_in[14];
  const void* pb1 = d_in[15];
  const void* P2  = d_in[16];
  const void* pb2 = d_in[17];
  const void* P3  = d_in[18];
  const void* pb3 = d_in[19];
  (void)d_ws; (void)ws_size; (void)in_sizes; (void)n_in; (void)out_size;

  // --- probe + atomic-free CSR build (separate launches: r15 lesson) ---
  probe_dtype_kernel<<<1, 256, 0, stream>>>(x);
  prep1_kernel<<<12500 + NHB + 81, 256, 0, stream>>>(x, dst, W1, W2, W3, P1);
  bucket_scan_kernel<<<NBKT, 256, 0, stream>>>();
  scatter_bucket_kernel<<<NHB, 256, 0, stream>>>(src, dst, w_edge);
  csr_finalize_kernel<<<NBKT, 256, 0, stream>>>();

  int gHop = (NN + 3) / 4;
  int gGemm = (NN + 63) / 64;

  // --- Layer 1: f0 = x(bf16); hop1 finalizes edge weights (FINW) ---
  hop_kernel<0, 5, true><<<gHop, 256, 0, stream>>>();
  hop_kernel<5, 6, false><<<gHop, 256, 0, stream>>>();
  hop_kernel<6, 7, false><<<gHop, 256, 0, stream>>>();
  gemm_kernel<0, 3, 1><<<gGemm, 256, 0, stream>>>(b1);

  // --- Layer 2: f0 = Hn0 ---
  hop_kernel<3, 5, false><<<gHop, 256, 0, stream>>>();
  hop_kernel<5, 6, false><<<gHop, 256, 0, stream>>>();
  hop_kernel<6, 7, false><<<gHop, 256, 0, stream>>>();
  gemm_kernel<3, 4, 2><<<gGemm, 256, 0, stream>>>(b2);

  // --- Layer 3 (Horner): out = Z0+b3 + A(Z1 + A(Z2 + A Z3)), Z_k = Hn1@W3_k ---
  gemm64_all_kernel<<<gGemm, 256, 0, stream>>>(b3);  // Z3,Z2,Z1,Z0+b3 fused
  hop64_kernel<8, 9, 12, false><<<gHop, 256, 0, stream>>>(nullptr);   // T1 = A Z3 + Z2
  hop64_kernel<12, 10, 13, false><<<gHop, 256, 0, stream>>>(nullptr); // T2 = A T1 + Z1
  hop64_kernel<13, 11, 12, true><<<gHop, 256, 0, stream>>>(d_out);    // h = A T2 + Z0

  // --- Predictor (pos+neg fused, MFMA) ---
  predictor_kernel<<<(2 * PP) / (4 * 16), 256, 0, stream>>>(pos_src, pos_dst, neg_src, neg_dst,
                                                            pb1, P2, pb2, P3, pb3, d_out);
}

// Round 8
// 461.096 us; speedup vs baseline: 1.6207x; 1.0508x over previous
//
#include <hip/hip_runtime.h>
#include <hip/hip_bf16.h>

typedef unsigned short u16;
typedef unsigned int u32;
typedef short short8v __attribute__((ext_vector_type(8)));
typedef float f32x4 __attribute__((ext_vector_type(4)));
typedef u32 u32x4 __attribute__((ext_vector_type(4)));

#define NN 50000
#define EE 800000
#define PP 65536
#define NBKT 196      // node buckets of 256: ceil(NN/256)
#define NHB 256       // histogram blocks (edge chunks of 3125)
#define ECH 3125      // edges per histogram block: 256*3125 = EE exactly

// ---- static device workspace. RULE (r3): device-global addresses never cross
// the host/device boundary — kernels resolve them via compile-time IDs.
// RULE (r15): NO cooperative launch / grid.sync on this chip — 512-block cap +
// cross-XCD barrier spin made one fused kernel 2.5x slower than the chain.
__device__ __align__(256) float g_deg_norm[NN];
__device__ __align__(256) int   g_row_ptr[NN + 1];
__device__ __align__(256) int   g_rank[EE];          // intra-node rank
__device__ __align__(256) int   g_bh[NBKT * NHB];    // [bucket][block] counts
__device__ __align__(256) int   g_bbase[NBKT * NHB]; // exclusive scan over blocks
__device__ __align__(256) int   g_btot[NBKT];
__device__ __align__(256) u32   g_ebkt[EE];          // bucket-grouped: src | dlow<<16
__device__ __align__(256) float g_wtmp[EE];          // raw w (f32), bucket-grouped
__device__ __align__(256) float g_w2[EE];            // raw w, CSR order
__device__ __align__(256) u32   g_ecwp[EE];          // final: src(16b) | w_bf16(16b)
__device__ __align__(256) u16   g_X16[NN * 128];     // x bf16, row-major
__device__ __align__(256) u16   g_H1[NN * 128];      // hop outs / 2x Z (layer-3 Horner)
__device__ __align__(256) u16   g_H2[NN * 128];
__device__ __align__(256) u16   g_H3[NN * 128];
__device__ __align__(256) u16   g_Hn0[NN * 128];
__device__ __align__(256) u16   g_Hn1[NN * 128];
__device__ __align__(256) u16   g_Hf16[NN * 64];     // final h (bf16), row-major
__device__ __align__(256) u16   g_Bf1[512 * 128];    // W in MFMA B-fragment order
__device__ __align__(256) u16   g_Bf2[512 * 128];
__device__ __align__(256) u16   g_Bf3[512 * 64];
__device__ __align__(256) u16   g_Pf1[4 * 64 * 8];   // P1 in B-frag order
__device__ int g_f32mode;  // 1 if harness float tensors are float32, 0 if bf16

__device__ __forceinline__ float bf2f(u16 u) {
  union { u32 i; float f; } v;
  v.i = ((u32)u) << 16;
  return v.f;
}
__device__ __forceinline__ u16 f2bf(float f) {
  u32 x = __float_as_uint(f);
  u32 r = (x + 0x7fffu + ((x >> 16) & 1u)) >> 16;  // RNE
  return (u16)r;
}
__device__ __forceinline__ float ldf(const void* p, int i, int m) {
  return m ? ((const float*)p)[i] : bf2f(((const u16*)p)[i]);
}

// buffer IDs: 0 = X16, 3 = Hn0, 4 = Hn1, 5 = H1, 6 = H2, 7 = H3 (stride 128)
template <int ID>
__device__ __forceinline__ u16* sel_buf() {
  if (ID == 0) return g_X16;
  if (ID == 3) return g_Hn0;
  if (ID == 4) return g_Hn1;
  if (ID == 5) return g_H1;
  if (ID == 6) return g_H2;
  return g_H3;
}
template <int ID>
__device__ __forceinline__ u16* sel_bf() {
  if (ID == 1) return g_Bf1;
  if (ID == 2) return g_Bf2;
  return g_Bf3;
}
// width-64 Z/T buffers for layer-3 Horner (carved from H1/H2/H3)
template <int ID>
__device__ __forceinline__ u16* zb() {
  if (ID == 8) return g_H1;                 // Z3
  if (ID == 9) return g_H1 + NN * 64;       // Z2
  if (ID == 10) return g_H2;                // Z1
  if (ID == 11) return g_H2 + NN * 64;      // Z0 (+bias)
  if (ID == 12) return g_H3;                // T ping
  return g_H3 + NN * 64;                    // 13: T pong
}

// -------------------------------------------------------------- dtype probe
__global__ void probe_dtype_kernel(const u16* __restrict__ x) {
  __shared__ int cnt;
  if (threadIdx.x == 0) cnt = 0;
  __syncthreads();
  int c = 0;
  for (int i = threadIdx.x; i < 2048; i += 256) {
    u16 u = x[2 * i];
    int e = (u >> 7) & 0xFF;
    if (e >= 0x8F) c++;
  }
  atomicAdd(&cnt, c);
  __syncthreads();
  if (threadIdx.x == 0) g_f32mode = (cnt > 64) ? 1 : 0;
}

// ---------------- fused prep1: x->bf16 | bucket histogram | W/P convert
// blocks [0,12500): convert x; [12500,12756): LDS bucket-hist of dst>>8;
// [12756,12837): W1/W2/W3/P1 -> B-frag order. (r14-proven)
template <int FOUT>
__device__ __forceinline__ void conv_w_body(const void* W, u16* dstbuf, int t, int m) {
  constexpr int NT = FOUT / 16;
  if (t >= 1024 * NT) return;
  int lane = t & 63;
  int rest = t >> 6;
  int nt = rest % NT;
  int s = (rest / NT) % 4;
  int kc = rest / (NT * 4);
  int kbase = kc * 128 + s * 32 + ((lane >> 4) << 3);
  int n = nt * 16 + (lane & 15);
  u16* dst = dstbuf + (size_t)t * 8;
#pragma unroll
  for (int j = 0; j < 8; ++j) dst[j] = f2bf(ldf(W, (kbase + j) * FOUT + n, m));
}
__global__ void prep1_kernel(const void* __restrict__ x, const int* __restrict__ dst,
                             const void* __restrict__ W1, const void* __restrict__ W2,
                             const void* __restrict__ W3, const void* __restrict__ P1) {
  __shared__ int lhist[NBKT];
  int b = blockIdx.x, tid = threadIdx.x;
  int m = g_f32mode;
  if (b < 12500) {
    int i = b * 256 + tid;  // u32-pair index, exact: 12500*256 = NN*64
    u32 lo = f2bf(ldf(x, 2 * i, m));
    u32 hi = f2bf(ldf(x, 2 * i + 1, m));
    ((u32*)g_X16)[i] = lo | (hi << 16);
  } else if (b < 12500 + NHB) {
    int hb = b - 12500;
    for (int i = tid; i < NBKT; i += 256) lhist[i] = 0;
    __syncthreads();
    int base = hb * ECH;
    for (int i = tid; i < ECH; i += 256) atomicAdd(&lhist[dst[base + i] >> 8], 1);
    __syncthreads();
    if (tid < NBKT) g_bh[tid * NHB + hb] = lhist[tid];
  } else {
    int wb = b - (12500 + NHB);
    if (wb < 32) {
      conv_w_body<128>(W1, g_Bf1, wb * 256 + tid, m);
    } else if (wb < 64) {
      conv_w_body<128>(W2, g_Bf2, (wb - 32) * 256 + tid, m);
    } else if (wb < 80) {
      conv_w_body<64>(W3, g_Bf3, (wb - 64) * 256 + tid, m);
    } else {
      int f = tid >> 6, lane = tid & 63;
      int ks = f >> 1, nt = f & 1;
      int quad = lane >> 4, arow = lane & 15;
#pragma unroll
      for (int j = 0; j < 8; ++j)
        g_Pf1[(size_t)tid * 8 + j] =
            f2bf(ldf(P1, (ks * 32 + quad * 8 + j) * 32 + nt * 16 + arow, m));
    }
  }
}

// ------------------------------------- S2: per-bucket exclusive scan over blocks
__global__ __launch_bounds__(256) void bucket_scan_kernel() {
  __shared__ int ws[4];
  int g = blockIdx.x, t = threadIdx.x;
  int v = g_bh[g * NHB + t];
  int x = v;
#pragma unroll
  for (int off = 1; off < 64; off <<= 1) {
    int y = __shfl_up(x, off, 64);
    if ((t & 63) >= off) x += y;
  }
  if ((t & 63) == 63) ws[t >> 6] = x;
  __syncthreads();
  int wp = 0;
  if (t >= 64) wp += ws[0];
  if (t >= 128) wp += ws[1];
  if (t >= 192) wp += ws[2];
  g_bbase[g * NHB + t] = wp + x - v;  // exclusive within bucket, block order
  if (t == 255) g_btot[g] = wp + x;
}

// --- local bucket-start scan helper: exclusive scan of g_btot into sb[] (LDS)
__device__ __forceinline__ void local_bstart(int* sb, int* ws, int tid) {
  int v = (tid < NBKT) ? g_btot[tid] : 0;
  int x = v;
#pragma unroll
  for (int off = 1; off < 64; off <<= 1) {
    int y = __shfl_up(x, off, 64);
    if ((tid & 63) >= off) x += y;
  }
  if ((tid & 63) == 63) ws[tid >> 6] = x;
  __syncthreads();
  int wp = 0;
  if (tid >= 64) wp += ws[0];
  if (tid >= 128) wp += ws[1];
  if (tid >= 192) wp += ws[2];
  if (tid < NBKT) sb[tid] = wp + x - v;
  if (tid == 0) sb[NBKT] = EE;
  __syncthreads();
}

// ---------------------------- S4: scatter edges into bucket-grouped order
__global__ __launch_bounds__(256) void scatter_bucket_kernel(const int* __restrict__ src,
                                                             const int* __restrict__ dst,
                                                             const void* __restrict__ w_edge) {
  __shared__ int sb[NBKT + 1];
  __shared__ int ws[4];
  __shared__ int lhist[NBKT];
  __shared__ int lbase[NBKT];
  int m = g_f32mode;
  int b = blockIdx.x, tid = threadIdx.x;
  local_bstart(sb, ws, tid);
  for (int i = tid; i < NBKT; i += 256) {
    lhist[i] = 0;
    lbase[i] = sb[i] + g_bbase[i * NHB + b];
  }
  __syncthreads();
  int base = b * ECH;
  for (int i = tid; i < ECH; i += 256) {
    int e = base + i;
    int d = dst[e];
    int s = src[e];
    float w = ldf(w_edge, e, m);
    int bkt = d >> 8;
    int r = atomicAdd(&lhist[bkt], 1);
    int pos = lbase[bkt] + r;
    g_ebkt[pos] = (u32)s | ((u32)(d & 255) << 16);
    g_wtmp[pos] = w;
  }
}

// ------------- S5: per-bucket CSR finalize: 256-bin LDS hist -> row_ptr,
// deg_norm, and in-bucket scatter to exact per-node segments.
__global__ __launch_bounds__(256) void csr_finalize_kernel() {
  __shared__ int sb[NBKT + 1];
  __shared__ int ws[4];
  __shared__ int hist[256];
  __shared__ int loff[256];
  int g = blockIdx.x, t = threadIdx.x;
  local_bstart(sb, ws, t);
  int bs = sb[g], be = sb[g + 1];
  hist[t] = 0;
  __syncthreads();
  for (int i = bs + t; i < be; i += 256) {
    int dlow = (g_ebkt[i] >> 16) & 0xFF;
    g_rank[i] = atomicAdd(&hist[dlow], 1);
  }
  __syncthreads();
  int v = hist[t];
  int x = v;
#pragma unroll
  for (int off = 1; off < 64; off <<= 1) {
    int y = __shfl_up(x, off, 64);
    if ((t & 63) >= off) x += y;
  }
  if ((t & 63) == 63) ws[t >> 6] = x;
  __syncthreads();
  int wp = 0;
  if (t >= 64) wp += ws[0];
  if (t >= 128) wp += ws[1];
  if (t >= 192) wp += ws[2];
  int excl = wp + x - v;
  loff[t] = excl;
  int node = g * 256 + t;
  if (node < NN) {
    g_row_ptr[node] = bs + excl;
    g_deg_norm[node] = rsqrtf((float)(v > 0 ? v : 1));
  }
  if (g == NBKT - 1 && t == 0) g_row_ptr[NN] = EE;
  __syncthreads();
  for (int i = bs + t; i < be; i += 256) {
    u32 p = g_ebkt[i];
    int dlow = (p >> 16) & 0xFF;
    int pos = bs + loff[dlow] + g_rank[i];
    g_ecwp[pos] = p;       // src in low 16; w field written by hop1 (FINW)
    g_w2[pos] = g_wtmp[i];
  }
}

// --------------------------------------------------------- width-128 hop (r21)
// out[n][f] = deg_norm[n] * sum_e w[e] * in[col[e]][f]
// r21: ONE 16-LANE GROUP PER NODE (4 nodes/wave). Lane = (grp=lane>>4 -> node,
// q=lane&15 -> features q*8..q*8+7). Each group walks its own edge list; each
// lane keeps full sums for its 8 features in registers -> NO cross-lane
// reduction, one 16B vector store per lane, row_ptr/store overhead amortized
// 4x (3125 blocks vs 12500). Gather bytes & ILP identical (4 rows/instr,
// unroll-4 in flight). Degree variance costs ~25% masked VALU slots only.
// FINW (layer-1 hop1): w = g_w2[e]*deg_norm[src] per-lane (f32), finalized
// bf16 edge written back by the owning lane (race-free, replay-safe).
template <int IN_ID, int OUT_ID, bool FINW>
__global__ __launch_bounds__(256) void hop_kernel() {
  int lane = threadIdx.x & 63;
  int wv = threadIdx.x >> 6;
  int grp = lane >> 4;  // node slot in wave
  int q = lane & 15;    // feature block
  int n = blockIdx.x * 16 + wv * 4 + grp;  // NN%16==0 -> no OOB (grid exact)
  const u16* inf = sel_buf<IN_ID>() + q * 8;
  int beg = g_row_ptr[n], end = g_row_ptr[n + 1];
  int sl = grp << 4;  // shfl base lane of this group
  float a[8];
#pragma unroll
  for (int j = 0; j < 8; ++j) a[j] = 0.f;
  for (int c = beg; c < end; c += 16) {
    int cnt = end - c;
    if (cnt > 16) cnt = 16;
    u32 myp = 0;
    float wf = 0.f;
    if (q < cnt) {
      myp = g_ecwp[c + q];
      if (FINW) {
        wf = g_w2[c + q] * g_deg_norm[myp & 0xFFFFu];
        g_ecwp[c + q] = (myp & 0xFFFFu) | ((u32)f2bf(wf) << 16);
      } else {
        wf = bf2f((u16)(myp >> 16));
      }
    }
    int i = 0;
    for (; i + 4 <= cnt; i += 4) {
      u32 p0 = __shfl(myp, sl + i, 64);
      u32 p1 = __shfl(myp, sl + i + 1, 64);
      u32 p2 = __shfl(myp, sl + i + 2, 64);
      u32 p3 = __shfl(myp, sl + i + 3, 64);
      float w0 = __shfl(wf, sl + i, 64);
      float w1 = __shfl(wf, sl + i + 1, 64);
      float w2 = __shfl(wf, sl + i + 2, 64);
      float w3 = __shfl(wf, sl + i + 3, 64);
      short8v u0 = *(const short8v*)(inf + (p0 & 0xFFFFu) * 128);
      short8v u1 = *(const short8v*)(inf + (p1 & 0xFFFFu) * 128);
      short8v u2 = *(const short8v*)(inf + (p2 & 0xFFFFu) * 128);
      short8v u3 = *(const short8v*)(inf + (p3 & 0xFFFFu) * 128);
#pragma unroll
      for (int j = 0; j < 8; ++j) {
        a[j] += w0 * bf2f((u16)u0[j]);
        a[j] += w1 * bf2f((u16)u1[j]);
        a[j] += w2 * bf2f((u16)u2[j]);
        a[j] += w3 * bf2f((u16)u3[j]);
      }
    }
    for (; i < cnt; ++i) {
      u32 p = __shfl(myp, sl + i, 64);
      float w = __shfl(wf, sl + i, 64);
      short8v u = *(const short8v*)(inf + (p & 0xFFFFu) * 128);
#pragma unroll
      for (int j = 0; j < 8; ++j) a[j] += w * bf2f((u16)u[j]);
    }
  }
  float dn = g_deg_norm[n];
  u32x4 o;
#pragma unroll
  for (int j = 0; j < 4; ++j)
    o[j] = (u32)f2bf(a[2 * j] * dn) | ((u32)f2bf(a[2 * j + 1] * dn) << 16);
  *(u32x4*)(sel_buf<OUT_ID>() + n * 128 + q * 8) = o;  // 16B/lane, 1KB/wave
}

// ------------------------------------------------- width-64 hop with addend
// T_out[n] = deg_norm[n] * (A T_in)[n] + Add[n]   (layer-3 Horner step)
// r21: one 8-LANE group per node (8 nodes/wave), same registered scheme.
template <int IN_ID, int ADD_ID, int OUT_ID, bool FINAL>
__global__ __launch_bounds__(256) void hop64_kernel(void* __restrict__ outp) {
  int lane = threadIdx.x & 63;
  int wv = threadIdx.x >> 6;
  int grp = lane >> 3;  // node slot 0..7
  int q = lane & 7;     // feature block (8 x 8 = 64 feats)
  int n = blockIdx.x * 32 + wv * 8 + grp;
  if (n >= NN) return;  // no barriers -> safe
  const u16* inf = zb<IN_ID>() + q * 8;
  int beg = g_row_ptr[n], end = g_row_ptr[n + 1];
  int sl = grp << 3;
  float a[8];
#pragma unroll
  for (int j = 0; j < 8; ++j) a[j] = 0.f;
  for (int c = beg; c < end; c += 8) {
    int cnt = end - c;
    if (cnt > 8) cnt = 8;
    u32 myp = 0;
    float wf = 0.f;
    if (q < cnt) {
      myp = g_ecwp[c + q];
      wf = bf2f((u16)(myp >> 16));
    }
    int i = 0;
    for (; i + 4 <= cnt; i += 4) {
      u32 p0 = __shfl(myp, sl + i, 64);
      u32 p1 = __shfl(myp, sl + i + 1, 64);
      u32 p2 = __shfl(myp, sl + i + 2, 64);
      u32 p3 = __shfl(myp, sl + i + 3, 64);
      float w0 = __shfl(wf, sl + i, 64);
      float w1 = __shfl(wf, sl + i + 1, 64);
      float w2 = __shfl(wf, sl + i + 2, 64);
      float w3 = __shfl(wf, sl + i + 3, 64);
      short8v u0 = *(const short8v*)(inf + (p0 & 0xFFFFu) * 64);
      short8v u1 = *(const short8v*)(inf + (p1 & 0xFFFFu) * 64);
      short8v u2 = *(const short8v*)(inf + (p2 & 0xFFFFu) * 64);
      short8v u3 = *(const short8v*)(inf + (p3 & 0xFFFFu) * 64);
#pragma unroll
      for (int j = 0; j < 8; ++j) {
        a[j] += w0 * bf2f((u16)u0[j]);
        a[j] += w1 * bf2f((u16)u1[j]);
        a[j] += w2 * bf2f((u16)u2[j]);
        a[j] += w3 * bf2f((u16)u3[j]);
      }
    }
    for (; i < cnt; ++i) {
      u32 p = __shfl(myp, sl + i, 64);
      float w = __shfl(wf, sl + i, 64);
      short8v u = *(const short8v*)(inf + (p & 0xFFFFu) * 64);
#pragma unroll
      for (int j = 0; j < 8; ++j) a[j] += w * bf2f((u16)u[j]);
    }
  }
  float dn = g_deg_norm[n];
  int ci = n * 64 + q * 8;
  u32x4 ad = *(const u32x4*)(zb<ADD_ID>() + ci);
  float r[8];
#pragma unroll
  for (int j = 0; j < 4; ++j) {
    r[2 * j] = a[2 * j] * dn + bf2f((u16)ad[j]);
    r[2 * j + 1] = a[2 * j + 1] * dn + bf2f((u16)(ad[j] >> 16));
  }
  u32x4 o;
#pragma unroll
  for (int j = 0; j < 4; ++j)
    o[j] = (u32)f2bf(r[2 * j]) | ((u32)f2bf(r[2 * j + 1]) << 16);
  if (!FINAL) {
    *(u32x4*)(zb<OUT_ID>() + ci) = o;
  } else {
    *(u32x4*)(g_Hf16 + ci) = o;
    if (g_f32mode) {
#pragma unroll
      for (int j = 0; j < 8; ++j) ((float*)outp)[2 * PP + ci + j] = r[j];
    } else {
      *(u32x4*)((u16*)outp + 2 * PP + ci) = o;
    }
  }
}

// -------------------------------------------------- MFMA GEMM (FOUT=128)
// C(M x 128) = [f0 | H1 | H2 | H3] (Mx512, row-major) @ B + bias, ReLU.
template <int A0_ID, int C_ID, int BF_ID>
__global__ __launch_bounds__(256) void gemm_kernel(const void* __restrict__ bias) {
  constexpr int NT = 8;
  const u16* Bf = sel_bf<BF_ID>();
  int tid = threadIdx.x;
  int lane = tid & 63, wv = tid >> 6;
  int quad = lane >> 4, arow = lane & 15;
  int mbase = blockIdx.x * 64 + wv * 16;
  if (mbase >= NN) return;  // no barriers -> safe (NN % 16 == 0)
  int row0 = mbase + arow;

  f32x4 acc[NT];
#pragma unroll
  for (int nt = 0; nt < NT; ++nt) acc[nt] = (f32x4){0.f, 0.f, 0.f, 0.f};

#pragma unroll
  for (int kc = 0; kc < 4; ++kc) {
    const u16* base = (kc == 0) ? sel_buf<A0_ID>() : (kc == 1) ? g_H1 : (kc == 2) ? g_H2 : g_H3;
#pragma unroll
    for (int s = 0; s < 4; ++s) {
      int ko = s * 32 + quad * 8;
      short8v av = *(const short8v*)(base + row0 * 128 + ko);
      const u16* bp = Bf + (size_t)(((kc * 4 + s) * NT) * 64 + lane) * 8;
#pragma unroll
      for (int nt = 0; nt < NT; ++nt) {
        short8v b = *(const short8v*)(bp + nt * 64 * 8);
        acc[nt] = __builtin_amdgcn_mfma_f32_16x16x32_bf16(av, b, acc[nt], 0, 0, 0);
      }
    }
  }

  int m = g_f32mode;
  float bn[NT];
#pragma unroll
  for (int nt = 0; nt < NT; ++nt) bn[nt] = ldf(bias, nt * 16 + arow, m);
#pragma unroll
  for (int i = 0; i < 4; ++i) {
    int row = mbase + quad * 4 + i;  // C/D: col=lane&15, row=quad*4+reg
#pragma unroll
    for (int nt = 0; nt < NT; ++nt) {
      float v = acc[nt][i] + bn[nt];
      v = v > 0.f ? v : 0.f;  // ReLU (layers 1,2 only)
      sel_buf<C_ID>()[row * 128 + nt * 16 + arow] = f2bf(v);
    }
  }
}

// --------------------- fused small GEMM: Z_k = Hn1 @ W3[kc] for kc=0..3
// (r13-proven) One pass over Hn1 computes all four width-64 Z buffers.
__global__ __launch_bounds__(256) void gemm64_all_kernel(const void* __restrict__ bias) {
  int tid = threadIdx.x;
  int lane = tid & 63, wv = tid >> 6;
  int quad = lane >> 4, arow = lane & 15;
  int mbase = blockIdx.x * 64 + wv * 16;
  if (mbase >= NN) return;
  int row0 = mbase + arow;

  f32x4 acc[4][4];  // [kc][nt]
#pragma unroll
  for (int kc = 0; kc < 4; ++kc)
#pragma unroll
    for (int nt = 0; nt < 4; ++nt) acc[kc][nt] = (f32x4){0.f, 0.f, 0.f, 0.f};

#pragma unroll
  for (int s = 0; s < 4; ++s) {
    int ko = s * 32 + quad * 8;
    short8v av = *(const short8v*)(g_Hn1 + row0 * 128 + ko);
#pragma unroll
    for (int kc = 0; kc < 4; ++kc) {
      const u16* bp = g_Bf3 + (size_t)(((kc * 4 + s) * 4) * 64 + lane) * 8;
#pragma unroll
      for (int nt = 0; nt < 4; ++nt) {
        short8v b = *(const short8v*)(bp + nt * 64 * 8);
        acc[kc][nt] = __builtin_amdgcn_mfma_f32_16x16x32_bf16(av, b, acc[kc][nt], 0, 0, 0);
      }
    }
  }

  int m = g_f32mode;
  float bn[4];
#pragma unroll
  for (int nt = 0; nt < 4; ++nt) bn[nt] = ldf(bias, nt * 16 + arow, m);
#pragma unroll
  for (int kc = 0; kc < 4; ++kc) {
    u16* Z = (kc == 0) ? zb<11>() : (kc == 1) ? zb<10>() : (kc == 2) ? zb<9>() : zb<8>();
#pragma unroll
    for (int i = 0; i < 4; ++i) {
      int row = mbase + quad * 4 + i;
#pragma unroll
      for (int nt = 0; nt < 4; ++nt) {
        float v = acc[kc][nt][i] + (kc == 0 ? bn[nt] : 0.f);
        Z[row * 64 + nt * 16 + arow] = f2bf(v);
      }
    }
  }
}

// ------------------------------------------------------------------ predictor
__global__ __launch_bounds__(256) void predictor_kernel(
    const int* __restrict__ pos_src, const int* __restrict__ pos_dst,
    const int* __restrict__ neg_src, const int* __restrict__ neg_dst,
    const void* __restrict__ pb1, const void* __restrict__ P2,
    const void* __restrict__ pb2, const void* __restrict__ P3, const void* __restrict__ pb3,
    void* __restrict__ out) {
  __shared__ float sP2[32 * 16];
  __shared__ float sb1[32], sb2[16], sP3[16];
  __shared__ float sb3;
  __shared__ float zt[4][16][33];
  int m = g_f32mode;
  int tid = threadIdx.x;
  for (int i = tid; i < 512; i += 256) sP2[i] = ldf(P2, i, m);
  if (tid < 32) sb1[tid] = ldf(pb1, tid, m);
  if (tid < 16) sb2[tid] = ldf(pb2, tid, m);
  if (tid < 16) sP3[tid] = ldf(P3, tid, m);
  if (tid == 0) sb3 = ldf(pb3, 0, m);
  __syncthreads();

  int wv = tid >> 6, lane = tid & 63;
  int quad = lane >> 4, arow = lane & 15;
  int base = (blockIdx.x * 4 + wv) * 16;
  int idx = base + arow;
  int s, d;
  if (idx < PP) { s = pos_src[idx]; d = pos_dst[idx]; }  // PP%16==0 -> wave-uniform
  else          { s = neg_src[idx - PP]; d = neg_dst[idx - PP]; }

  const u16* hs = g_Hf16 + s * 64 + quad * 8;
  const u16* hd = g_Hf16 + d * 64 + quad * 8;
  short8v zf[2];
#pragma unroll
  for (int ks = 0; ks < 2; ++ks) {
    short8v a = *(const short8v*)(hs + ks * 32);
    short8v b = *(const short8v*)(hd + ks * 32);
#pragma unroll
    for (int j = 0; j < 8; ++j)
      ((u16*)&zf[ks])[j] = f2bf(bf2f((u16)a[j]) * bf2f((u16)b[j]));
  }
  f32x4 acc[2];
  acc[0] = (f32x4){0.f, 0.f, 0.f, 0.f};
  acc[1] = (f32x4){0.f, 0.f, 0.f, 0.f};
#pragma unroll
  for (int ks = 0; ks < 2; ++ks) {
#pragma unroll
    for (int nt = 0; nt < 2; ++nt) {
      short8v bfr = *(const short8v*)(g_Pf1 + (size_t)((ks * 2 + nt) * 64 + lane) * 8);
      acc[nt] = __builtin_amdgcn_mfma_f32_16x16x32_bf16(zf[ks], bfr, acc[nt], 0, 0, 0);
    }
  }
#pragma unroll
  for (int nt = 0; nt < 2; ++nt) {
    float bn = sb1[nt * 16 + arow];
#pragma unroll
    for (int i = 0; i < 4; ++i) {
      float v = acc[nt][i] + bn;
      zt[wv][quad * 4 + i][nt * 16 + arow] = v > 0.f ? v : 0.2f * v;
    }
  }
  __syncthreads();
  float z2[4];
#pragma unroll
  for (int jj = 0; jj < 4; ++jj) z2[jj] = sb2[quad * 4 + jj];
  const float* zrow = &zt[wv][arow][0];
#pragma unroll
  for (int c = 0; c < 32; ++c) {
    float zc = zrow[c];
#pragma unroll
    for (int jj = 0; jj < 4; ++jj) z2[jj] += zc * sP2[c * 16 + quad * 4 + jj];
  }
  float o = 0.f;
#pragma unroll
  for (int jj = 0; jj < 4; ++jj) {
    float v = z2[jj] > 0.f ? z2[jj] : 0.2f * z2[jj];
    o += v * sP3[quad * 4 + jj];
  }
  o += __shfl_xor(o, 16, 64);
  o += __shfl_xor(o, 32, 64);
  o += sb3;
  if (quad == 0) {
    if (m) ((float*)out)[idx] = o;
    else   ((u16*)out)[idx] = f2bf(o);
  }
}

// ------------------------------------------------------------------- launch
extern "C" void kernel_launch(void* const* d_in, const int* in_sizes, int n_in,
                              void* d_out, int out_size, void* d_ws, size_t ws_size,
                              hipStream_t stream) {
  const u16* x       = (const u16*)d_in[0];
  const int* src     = (const int*)d_in[1];
  const int* dst     = (const int*)d_in[2];
  const void* w_edge = d_in[3];
  const int* pos_src = (const int*)d_in[4];
  const int* pos_dst = (const int*)d_in[5];
  const int* neg_src = (const int*)d_in[6];
  const int* neg_dst = (const int*)d_in[7];
  const void* W1 = d_in[8];
  const void* b1 = d_in[9];
  const void* W2 = d_in[10];
  const void* b2 = d_in[11];
  const void* W3 = d_in[12];
  const void* b3 = d_in[13];
  const void* P1  = d_in[14];
  const void* pb1 = d_in[15];
  const void* P2  = d_in[16];
  const void* pb2 = d_in[17];
  const void* P3  = d_in[18];
  const void* pb3 = d_in[19];
  (void)d_ws; (void)ws_size; (void)in_sizes; (void)n_in; (void)out_size;

  // --- probe + atomic-free CSR build (separate launches: r15 lesson) ---
  probe_dtype_kernel<<<1, 256, 0, stream>>>(x);
  prep1_kernel<<<12500 + NHB + 81, 256, 0, stream>>>(x, dst, W1, W2, W3, P1);
  bucket_scan_kernel<<<NBKT, 256, 0, stream>>>();
  scatter_bucket_kernel<<<NHB, 256, 0, stream>>>(src, dst, w_edge);
  csr_finalize_kernel<<<NBKT, 256, 0, stream>>>();

  int gHop = NN / 16;            // 3125, exact (16 nodes/block)
  int gHop64 = (NN + 31) / 32;   // 1563 (32 nodes/block)
  int gGemm = (NN + 63) / 64;

  // --- Layer 1: f0 = x(bf16); hop1 finalizes edge weights (FINW) ---
  hop_kernel<0, 5, true><<<gHop, 256, 0, stream>>>();
  hop_kernel<5, 6, false><<<gHop, 256, 0, stream>>>();
  hop_kernel<6, 7, false><<<gHop, 256, 0, stream>>>();
  gemm_kernel<0, 3, 1><<<gGemm, 256, 0, stream>>>(b1);

  // --- Layer 2: f0 = Hn0 ---
  hop_kernel<3, 5, false><<<gHop, 256, 0, stream>>>();
  hop_kernel<5, 6, false><<<gHop, 256, 0, stream>>>();
  hop_kernel<6, 7, false><<<gHop, 256, 0, stream>>>();
  gemm_kernel<3, 4, 2><<<gGemm, 256, 0, stream>>>(b2);

  // --- Layer 3 (Horner): out = Z0+b3 + A(Z1 + A(Z2 + A Z3)), Z_k = Hn1@W3_k ---
  gemm64_all_kernel<<<gGemm, 256, 0, stream>>>(b3);  // Z3,Z2,Z1,Z0+b3 fused
  hop64_kernel<8, 9, 12, false><<<gHop64, 256, 0, stream>>>(nullptr);   // T1 = A Z3 + Z2
  hop64_kernel<12, 10, 13, false><<<gHop64, 256, 0, stream>>>(nullptr); // T2 = A T1 + Z1
  hop64_kernel<13, 11, 12, true><<<gHop64, 256, 0, stream>>>(d_out);    // h = A T2 + Z0

  // --- Predictor (pos+neg fused, MFMA) ---
  predictor_kernel<<<(2 * PP) / (4 * 16), 256, 0, stream>>>(pos_src, pos_dst, neg_src, neg_dst,
                                                            pb1, P2, pb2, P3, pb3, d_out);
}